// Round 7
// baseline (839.540 us; speedup 1.0000x reference)
//
#include <hip/hip_runtime.h>
#include <math.h>

#define DEV __device__ __forceinline__

constexpr int DHc = 64;
constexpr int HDc = 512;
constexpr int Hc  = 8;
constexpr int BLKc = 128;

typedef float f32x16 __attribute__((ext_vector_type(16)));
typedef short s16x8  __attribute__((ext_vector_type(8)));

union FragU { unsigned u[4]; s16x8 v; };

// ---------- float <-> order-preserving uint ----------
DEV unsigned fenc(float f){ unsigned u = __float_as_uint(f); return (u & 0x80000000u) ? ~u : (u | 0x80000000u); }
DEV float fdec(unsigned u){ unsigned b = (u & 0x80000000u) ? (u ^ 0x80000000u) : ~u; return __uint_as_float(b); }
DEV float hv_calc(float c0, float c1, float h0, float h1){
  return __fadd_rn(__fmul_rn(c0, h0), __fmul_rn(c1, h1));
}
// bf16 encode (round-to-nearest-even) / decode
DEV unsigned short f2bf(float f){
  unsigned u = __float_as_uint(f);
  return (unsigned short)((u + 0x7FFFu + ((u >> 16) & 1u)) >> 16);
}
DEV float bf2f(unsigned short s){ return __uint_as_float((unsigned)s << 16); }

// pack two f32 -> bf16x2 (RNE), src0 -> low half
DEV unsigned cvtpk(float lo, float hi){
  unsigned r;
  asm("v_cvt_pk_bf16_f32 %0, %1, %2" : "=v"(r) : "v"(lo), "v"(hi));
  return r;
}
// v_permlane32_swap_b32
DEV void pswap(unsigned &a, unsigned &b){
  asm volatile("v_permlane32_swap_b32 %0, %1" : "+v"(a), "+v"(b));
}

// ---------- min/max reductions for sort keys ----------
__global__ void minmax_init_kernel(unsigned* mm){
  int t = threadIdx.x;
  if (t < 4) mm[t] = 0xFFFFFFFFu;
  else if (t < 8) mm[t] = 0u;
}

__global__ __launch_bounds__(256) void minmax_reduce_kernel(const float* __restrict__ coords,
    const float* __restrict__ hp, unsigned* mm, int N)
{
  __shared__ float red[4][8];
  float h[6];
  #pragma unroll
  for (int i = 0; i < 6; ++i) h[i] = hp[i];
  float mn[4] = {3.0e38f, 3.0e38f, 3.0e38f, 3.0e38f};
  float mx[4] = {-3.0e38f, -3.0e38f, -3.0e38f, -3.0e38f};
  for (int i = blockIdx.x*blockDim.x + threadIdx.x; i < N; i += gridDim.x*blockDim.x){
    float2 c = *(const float2*)&coords[2*i];
    float v0 = c.x;
    float v1 = hv_calc(c.x, c.y, h[0], h[1]);
    float v2 = hv_calc(c.x, c.y, h[2], h[3]);
    float v3 = hv_calc(c.x, c.y, h[4], h[5]);
    mn[0] = fminf(mn[0], v0); mx[0] = fmaxf(mx[0], v0);
    mn[1] = fminf(mn[1], v1); mx[1] = fmaxf(mx[1], v1);
    mn[2] = fminf(mn[2], v2); mx[2] = fmaxf(mx[2], v2);
    mn[3] = fminf(mn[3], v3); mx[3] = fmaxf(mx[3], v3);
  }
  #pragma unroll
  for (int o = 1; o < 64; o <<= 1){
    #pragma unroll
    for (int s = 0; s < 4; ++s){
      mn[s] = fminf(mn[s], __shfl_xor(mn[s], o));
      mx[s] = fmaxf(mx[s], __shfl_xor(mx[s], o));
    }
  }
  int w = threadIdx.x >> 6;
  if ((threadIdx.x & 63) == 0){
    #pragma unroll
    for (int s = 0; s < 4; ++s){ red[w][s] = mn[s]; red[w][4+s] = mx[s]; }
  }
  __syncthreads();
  int t = threadIdx.x;
  if (t < 4){
    float v = fminf(fminf(red[0][t], red[1][t]), fminf(red[2][t], red[3][t]));
    atomicMin(&mm[t], fenc(v));
  } else if (t < 8){
    float v = fmaxf(fmaxf(red[0][t], red[1][t]), fmaxf(red[2][t], red[3][t]));
    atomicMax(&mm[t], fenc(v));
  }
}

__global__ void make_keys_kernel(const float* __restrict__ coords, const int* __restrict__ batch,
                                 const float* __restrict__ hp, const unsigned* __restrict__ mm,
                                 unsigned long long* __restrict__ keys, int N)
{
  int i = blockIdx.x*blockDim.x + threadIdx.x;
  if (i >= N) return;
  float c0 = coords[2*i], c1 = coords[2*i+1];
  float c0min = fdec(mm[0]), c0max = fdec(mm[4]);
  float rf = (c0 - c0min) / (c0max - c0min + 1e-6f) * 8.0f;
  int region = (int)rf;
  region = region < 0 ? 0 : (region > 7 ? 7 : region);
  float base2 = ((float)batch[i] * 8.0f + (float)region) * 2.0f;
  #pragma unroll
  for (int r = 0; r < 3; ++r){
    float hv = hv_calc(c0, c1, hp[2*r], hp[2*r+1]);
    float hn = (hv - fdec(mm[1+r])) / (fdec(mm[5+r]) - fdec(mm[1+r]) + 1e-6f);
    float skey = base2 + hn;
    keys[(size_t)r*N + i] = ((unsigned long long)__float_as_uint(skey) << 32) | (unsigned)i;
  }
}

// ---------- bitonic sort, 8192-element local tiles (4 pairs/thread) ----------
__global__ __launch_bounds__(1024) void bitonic_local_full8k_kernel(unsigned long long* keys, int N)
{
  __shared__ unsigned long long sh[8192];
  unsigned long long* a = keys + (size_t)blockIdx.y * N;
  int base = blockIdx.x * 8192, t = threadIdx.x;
  #pragma unroll
  for (int e = 0; e < 8; ++e) sh[t + e*1024] = a[base + t + e*1024];
  __syncthreads();
  for (int k = 2; k <= 8192; k <<= 1){
    for (int j = k >> 1; j > 0; j >>= 1){
      #pragma unroll
      for (int p = 0; p < 4; ++p){
        int pi = t + p*1024;
        int i = ((pi & ~(j-1)) << 1) | (pi & (j-1));
        bool dirup = (((base + i) & k) == 0);
        unsigned long long x = sh[i], y = sh[i+j];
        if ((x > y) == dirup){ sh[i] = y; sh[i+j] = x; }
      }
      __syncthreads();
    }
  }
  #pragma unroll
  for (int e = 0; e < 8; ++e) a[base + t + e*1024] = sh[t + e*1024];
}

__global__ void bitonic_global_kernel(unsigned long long* keys, int N, int k, int j)
{
  unsigned long long* a = keys + (size_t)blockIdx.y * N;
  int i = blockIdx.x*blockDim.x + threadIdx.x;
  int l = i ^ j;
  if (l > i && l < N){
    unsigned long long x = a[i], y = a[l];
    bool dirup = ((i & k) == 0);
    if ((x > y) == dirup){ a[i] = y; a[l] = x; }
  }
}

__global__ __launch_bounds__(1024) void bitonic_local_merge8k_kernel(unsigned long long* keys, int N, int k)
{
  __shared__ unsigned long long sh[8192];
  unsigned long long* a = keys + (size_t)blockIdx.y * N;
  int base = blockIdx.x * 8192, t = threadIdx.x;
  #pragma unroll
  for (int e = 0; e < 8; ++e) sh[t + e*1024] = a[base + t + e*1024];
  __syncthreads();
  for (int j = 4096; j > 0; j >>= 1){
    #pragma unroll
    for (int p = 0; p < 4; ++p){
      int pi = t + p*1024;
      int i = ((pi & ~(j-1)) << 1) | (pi & (j-1));
      bool dirup = (((base + i) & k) == 0);
      unsigned long long x = sh[i], y = sh[i+j];
      if ((x > y) == dirup){ sh[i] = y; sh[i+j] = x; }
    }
    __syncthreads();
  }
  #pragma unroll
  for (int e = 0; e < 8; ++e) a[base + t + e*1024] = sh[t + e*1024];
}

__global__ void extract_idx_kernel(const unsigned long long* __restrict__ keys, int* __restrict__ idx, int total)
{
  int i = blockIdx.x*blockDim.x + threadIdx.x;
  if (i < total) idx[i] = (int)(keys[i] & 0xFFFFFFFFull);
}

// ---------- weight convert+transpose (once): wqkvT[l][z][n][k], woT[l][n][k] ----------
__global__ void wconv_kernel(const float* __restrict__ wq, const float* __restrict__ wk,
                             const float* __restrict__ wv, const float* __restrict__ wo,
                             unsigned short* __restrict__ wqkvT, unsigned short* __restrict__ woT)
{
  int tid = blockIdx.x*blockDim.x + threadIdx.x;
  const int NQ = 4*3*512*64;
  if (tid < NQ){
    int kk = tid & 63;
    int rest = tid >> 6;
    int n = rest & 511;
    int rest2 = rest >> 9;
    int z = rest2 % 3, l = rest2 / 3;
    const float* W = (z==0) ? wq : (z==1) ? wk : wv;
    wqkvT[tid] = f2bf(W[((size_t)l*64 + kk)*512 + n]);
  } else if (tid < NQ + 4*64*512){
    int e = tid - NQ;
    int kk = e & 511;
    int rest = e >> 9;
    int n = rest & 63;
    int l = rest >> 6;
    woT[e] = f2bf(wo[((size_t)l*512 + kk)*64 + n]);
  }
}

// ---------- encoder: h0 = relu(x@W1+b1)@W2+b2; fused LN(layer0) -> xnb ----------
__global__ __launch_bounds__(256) void encoder_kernel(const float* __restrict__ x,
    const float* __restrict__ W1, const float* __restrict__ b1,
    const float* __restrict__ W2, const float* __restrict__ b2,
    const float* __restrict__ lng, const float* __restrict__ lnb,
    float* __restrict__ h0, unsigned short* __restrict__ xnb, int N)
{
  __shared__ float W1s[16][64];
  __shared__ __align__(16) float W2s[64][64];
  __shared__ float xs[4][16];
  __shared__ float t1s[4][64];
  int t = threadIdx.x;
  for (int f = t; f < 1024; f += 256) W1s[f>>6][f&63] = W1[f];
  #pragma unroll
  for (int e = 0; e < 4; ++e){ int f = t + e*256; *(float4*)&W2s[f>>4][(f&15)*4] = *(const float4*)&W2[f*4]; }
  int w = t >> 6, d = t & 63;
  int row = blockIdx.x*4 + w;
  if (d < 16) xs[w][d] = x[(size_t)row*16 + d];
  __syncthreads();
  float acc = b1[d];
  #pragma unroll
  for (int i = 0; i < 16; ++i) acc += xs[w][i]*W1s[i][d];
  t1s[w][d] = fmaxf(acc, 0.f);
  __syncthreads();
  float acc2 = b2[d];
  #pragma unroll
  for (int i = 0; i < 64; ++i) acc2 += t1s[w][i]*W2s[i][d];
  h0[(size_t)row*64 + d] = acc2;
  // fused LN for layer 0
  float s = acc2;
  #pragma unroll
  for (int o = 1; o < 64; o <<= 1) s += __shfl_xor(s, o);
  float mean = s * (1.0f/64.0f);
  float dv = acc2 - mean, sq = dv*dv;
  #pragma unroll
  for (int o = 1; o < 64; o <<= 1) sq += __shfl_xor(sq, o);
  xnb[(size_t)row*64 + d] = f2bf(dv * rsqrtf(sq*(1.0f/64.0f) + 1e-5f) * lng[d] + lnb[d]);
}

// ---------- QKV MFMA GEMM: C[N x 512](bf16) = xnb[N x 64] @ W; q pre-scaled by 0.125 ----------
__global__ __launch_bounds__(256) void qkv_mfma_kernel(
    const unsigned short* __restrict__ xnb, const unsigned short* __restrict__ wqkvT_l,
    unsigned short* __restrict__ q, unsigned short* __restrict__ k, unsigned short* __restrict__ v, int N)
{
  __shared__ __align__(16) unsigned short a_lds[128*64];
  __shared__ __align__(16) unsigned short b_lds[128*64];
  int z = blockIdx.z;
  unsigned short* C = (z==0) ? q : (z==1) ? k : v;
  const unsigned short* wT = wqkvT_l + (size_t)z*512*64;
  float oscale = (z==0) ? 0.125f : 1.0f;
  int rb = blockIdx.x*128, cb = blockIdx.y*128;
  int t = threadIdx.x;
  #pragma unroll
  for (int e = 0; e < 4; ++e){
    int f = t + e*256; int row = f >> 3, ch = f & 7;
    *(s16x8*)&a_lds[row*64 + ((ch ^ (row&7))*8)] = *(const s16x8*)&xnb[(size_t)(rb+row)*64 + ch*8];
    *(s16x8*)&b_lds[row*64 + ((ch ^ (row&7))*8)] = *(const s16x8*)&wT[(size_t)(cb+row)*64 + ch*8];
  }
  __syncthreads();
  int w = t >> 6, l = t & 63, lo = l & 31, hi = l >> 5;
  s16x8 bf[4];
  #pragma unroll
  for (int ks = 0; ks < 4; ++ks){
    int brow = w*32 + lo, s = (ks<<1)|hi;
    bf[ks] = *(const s16x8*)&b_lds[brow*64 + ((s ^ (brow&7))*8)];
  }
  f32x16 acc[4];
  #pragma unroll
  for (int mt = 0; mt < 4; ++mt)
    #pragma unroll
    for (int i = 0; i < 16; ++i) acc[mt][i] = 0.f;
  #pragma unroll
  for (int mt = 0; mt < 4; ++mt){
    int arow = mt*32 + lo;
    #pragma unroll
    for (int ks = 0; ks < 4; ++ks){
      int s = (ks<<1)|hi;
      s16x8 af = *(const s16x8*)&a_lds[arow*64 + ((s ^ (arow&7))*8)];
      acc[mt] = __builtin_amdgcn_mfma_f32_32x32x16_bf16(af, bf[ks], acc[mt], 0, 0, 0);
    }
  }
  #pragma unroll
  for (int mt = 0; mt < 4; ++mt)
    #pragma unroll
    for (int reg = 0; reg < 16; ++reg){
      int m = mt*32 + (reg&3) + 8*(reg>>2) + 4*hi;
      C[(size_t)(rb+m)*HDc + cb + w*32 + lo] = f2bf(acc[mt][reg]*oscale);
    }
}

// ---------- w_head (all 4 layers, once) ----------
__global__ void whead_kernel(const float* __restrict__ rpe, float* __restrict__ wh)
{
  int l = blockIdx.x >> 3, h = blockIdx.x & 7, d = threadIdx.x;
  const float* rp = rpe + (size_t)l*8*512;
  float s = 0.f;
  #pragma unroll
  for (int w = 0; w < 8; ++w) s += rp[(size_t)w*512 + h*64 + d];
  #pragma unroll
  for (int o = 1; o < 64; o <<= 1) s += __shfl_xor(s, o);
  if (d == 0){
    float m = s * (1.0f/512.0f);
    wh[blockIdx.x] = fmaxf(m, 0.f) + log1pf(expf(-fabsf(m)));
  }
}

// ============ fused single-pass MFMA attention (round-5 verified version) ============
__global__ __launch_bounds__(256, 3) void attn_kernel(
    const unsigned short* __restrict__ qm, const unsigned short* __restrict__ km,
    const unsigned short* __restrict__ vm,
    const float* __restrict__ coords, const int* __restrict__ batch,
    const int* __restrict__ idx_all, const float* __restrict__ w_head,
    float* __restrict__ lse_all, unsigned short* __restrict__ o_buf, int N)
{
  __shared__ __align__(16) unsigned short qlds[128*64];
  __shared__ __align__(16) unsigned short klds[128*64];
  __shared__ __align__(16) unsigned short vtl[64*128];   // V^T [d][k]
  __shared__ __align__(16) float c1s[BLKc];
  __shared__ __align__(16) int   bts[BLKc];
  __shared__ int   idxs[BLKc];
  __shared__ __align__(16) float isel[BLKc];
  __shared__ int unif;
  int b = blockIdx.x, h = blockIdx.y, r = blockIdx.z, t = threadIdx.x;
  const int* idx_r = idx_all + (size_t)r*N;
  if (t < BLKc){
    int g = idx_r[b*BLKc + t];
    idxs[t] = g; c1s[t] = coords[2*g+1]; bts[t] = batch[g];
  }
  __syncthreads();
  if (t == 0) unif = (bts[0] == bts[127]);
  #pragma unroll
  for (int e = 0; e < 4; ++e){
    int f = t + e*256;
    int row = f >> 3, ch = f & 7;
    int g = idxs[row];
    s16x8 qv = *(const s16x8*)&qm[(size_t)g*HDc + h*DHc + ch*8];
    s16x8 kv = *(const s16x8*)&km[(size_t)g*HDc + h*DHc + ch*8];
    *(s16x8*)&qlds[row*64 + ((ch ^ (row&7))*8)] = qv;
    *(s16x8*)&klds[row*64 + ((ch ^ (row&7))*8)] = kv;
  }
  #pragma unroll
  for (int e = 0; e < 2; ++e){
    int pf = t + e*256;
    int jp = pf >> 3, dc = pf & 7;
    int j0 = jp*2, j1 = j0+1;
    s16x8 v0 = *(const s16x8*)&vm[(size_t)idxs[j0]*HDc + h*DHc + dc*8];
    s16x8 v1 = *(const s16x8*)&vm[(size_t)idxs[j1]*HDc + h*DHc + dc*8];
    int cj = jp >> 2;
    int jo = jp & 3;
    #pragma unroll
    for (int i = 0; i < 8; ++i){
      int d = dc*8 + i;
      unsigned val = (unsigned)(unsigned short)v0[i] | ((unsigned)(unsigned short)v1[i] << 16);
      *(unsigned*)&vtl[d*128 + ((cj ^ (d&7))*8) + jo*2] = val;
    }
  }
  __syncthreads();

  int w = t >> 6, l = t & 63, lo = l & 31, hi = l >> 5;
  int qrow = w*32 + lo;

  s16x8 qf[4];
  #pragma unroll
  for (int ks = 0; ks < 4; ++ks)
    qf[ks] = *(const s16x8*)&qlds[qrow*64 + ((((ks<<1)|hi) ^ (qrow&7))*8)];

  f32x16 acc[4];
  #pragma unroll
  for (int kt = 0; kt < 4; ++kt)
    #pragma unroll
    for (int i = 0; i < 16; ++i) acc[kt][i] = 0.f;

  __builtin_amdgcn_s_setprio(1);
  #pragma unroll
  for (int kt = 0; kt < 4; ++kt){
    int krow = kt*32 + lo;
    #pragma unroll
    for (int ks = 0; ks < 4; ++ks){
      s16x8 kf = *(const s16x8*)&klds[krow*64 + ((((ks<<1)|hi) ^ (krow&7))*8)];
      acc[kt] = __builtin_amdgcn_mfma_f32_32x32x16_bf16(kf, qf[ks], acc[kt], 0, 0, 0);
    }
  }
  __builtin_amdgcn_s_setprio(0);

  float c1i = c1s[qrow]; int bti = bts[qrow];
  float wh = w_head[h];
  int msk = unif;
  #pragma unroll
  for (int kt = 0; kt < 4; ++kt){
    #pragma unroll
    for (int rq = 0; rq < 4; ++rq){
      int kb = kt*32 + rq*8 + hi*4;
      float4 c4 = *(const float4*)&c1s[kb];
      int4  b4 = *(const int4*)&bts[kb];
      #pragma unroll
      for (int j = 0; j < 4; ++j){
        int reg = rq*4 + j;
        float c1k = (j==0)?c4.x:(j==1)?c4.y:(j==2)?c4.z:c4.w;
        int   btk = (j==0)?b4.x:(j==1)?b4.y:(j==2)?b4.z:b4.w;
        float dd = c1i - c1k;
        float sc = acc[kt][reg] - wh*dd*dd;
        if (!msk && bti != btk) sc = -1e9f;
        acc[kt][reg] = sc;
      }
    }
  }

  float m = -3.0e38f;
  #pragma unroll
  for (int kt = 0; kt < 4; ++kt)
    #pragma unroll
    for (int i = 0; i < 16; ++i) m = fmaxf(m, acc[kt][i]);
  m = fmaxf(m, __shfl_xor(m, 32));
  float se = 0.f;
  #pragma unroll
  for (int kt = 0; kt < 4; ++kt)
    #pragma unroll
    for (int i = 0; i < 16; ++i){
      float p = __expf(acc[kt][i] - m);
      acc[kt][i] = p;
      se += p;
    }
  se += __shfl_xor(se, 32);
  if (l < 32){
    int gi0 = idxs[qrow];
    lse_all[((size_t)r*N + gi0)*Hc + h] = m + __logf(se);
    isel[qrow] = 1.0f / se;
  }

  f32x16 oa0, oa1;
  #pragma unroll
  for (int i = 0; i < 16; ++i){ oa0[i] = 0.f; oa1[i] = 0.f; }

  __builtin_amdgcn_s_setprio(1);
  #pragma unroll
  for (int kt = 0; kt < 4; ++kt){
    unsigned X = cvtpk(acc[kt][0],  acc[kt][1]);
    unsigned Z = cvtpk(acc[kt][2],  acc[kt][3]);
    unsigned Y = cvtpk(acc[kt][4],  acc[kt][5]);
    unsigned W = cvtpk(acc[kt][6],  acc[kt][7]);
    pswap(X, Y); pswap(Z, W);
    FragU f0; f0.u[0]=X; f0.u[1]=Z; f0.u[2]=Y; f0.u[3]=W;
    unsigned X2 = cvtpk(acc[kt][8],  acc[kt][9]);
    unsigned Z2 = cvtpk(acc[kt][10], acc[kt][11]);
    unsigned Y2 = cvtpk(acc[kt][12], acc[kt][13]);
    unsigned W2 = cvtpk(acc[kt][14], acc[kt][15]);
    pswap(X2, Y2); pswap(Z2, W2);
    FragU f1; f1.u[0]=X2; f1.u[1]=Z2; f1.u[2]=Y2; f1.u[3]=W2;
    #pragma unroll
    for (int hks = 0; hks < 2; ++hks){
      s16x8 pa = hks ? f1.v : f0.v;
      int kch = kt*4 + hks*2 + hi;
      int d0 = lo;
      s16x8 vf0 = *(const s16x8*)&vtl[d0*128 + ((kch ^ (d0&7))*8)];
      oa0 = __builtin_amdgcn_mfma_f32_32x32x16_bf16(pa, vf0, oa0, 0, 0, 0);
      int d1 = 32 + lo;
      s16x8 vf1 = *(const s16x8*)&vtl[d1*128 + ((kch ^ (d1&7))*8)];
      oa1 = __builtin_amdgcn_mfma_f32_32x32x16_bf16(pa, vf1, oa1, 0, 0, 0);
    }
  }
  __builtin_amdgcn_s_setprio(0);

  unsigned short* orow = o_buf + (size_t)r*N*HDc;
  #pragma unroll
  for (int rq = 0; rq < 4; ++rq){
    float4 s4 = *(const float4*)&isel[w*32 + rq*8 + hi*4];
    #pragma unroll
    for (int j = 0; j < 4; ++j){
      int reg = rq*4 + j;
      int qq = rq*8 + hi*4 + j;
      int g = idxs[w*32 + qq];
      float sv = (j==0)?s4.x:(j==1)?s4.y:(j==2)?s4.z:s4.w;
      unsigned short* dst = &orow[(size_t)g*HDc + h*DHc + lo];
      dst[0]  = f2bf(oa0[reg]*sv);
      dst[32] = f2bf(oa1[reg]*sv);
    }
  }
  (void)b;
}

// ---------- WO MFMA with fused cross-round combine ----------
__global__ __launch_bounds__(256) void wo_mfma_kernel(
    const unsigned short* __restrict__ o_buf, const float* __restrict__ lse_all,
    const unsigned short* __restrict__ woT_l, float* __restrict__ cur, int N)
{
  __shared__ __align__(16) unsigned short As[64*128];
  __shared__ __align__(16) unsigned short Bs[64*128];
  __shared__ float wts[64][24];
  int rb = blockIdx.x*64, t = threadIdx.x;
  #pragma unroll
  for (int e = 0; e < 2; ++e){
    int p = t + e*256;
    int rr = p >> 3, h = p & 7;
    float l0 = lse_all[((size_t)0*N + rb+rr)*Hc + h];
    float l1 = lse_all[((size_t)1*N + rb+rr)*Hc + h];
    float l2 = lse_all[((size_t)2*N + rb+rr)*Hc + h];
    float lm = fmaxf(l0, fmaxf(l1, l2));
    float e0 = __expf(l0-lm), e1 = __expf(l1-lm), e2 = __expf(l2-lm);
    float inv = 1.0f/(e0+e1+e2);
    wts[rr][h*3+0] = e0*inv; wts[rr][h*3+1] = e1*inv; wts[rr][h*3+2] = e2*inv;
  }
  int w = t >> 6, l = t & 63, lo = l & 31, hi = l >> 5;
  int mt = w >> 1, nt = w & 1;
  f32x16 acc;
  #pragma unroll
  for (int i = 0; i < 16; ++i) acc[i] = 0.f;
  for (int kt = 0; kt < 4; ++kt){
    __syncthreads();
    #pragma unroll
    for (int e = 0; e < 4; ++e){
      int f = t + e*256; int rr = f >> 4, kc = f & 15;
      int k0 = kt*128 + kc*8;
      int h = k0 >> 6;
      float w0 = wts[rr][h*3+0], w1 = wts[rr][h*3+1], w2 = wts[rr][h*3+2];
      s16x8 u0 = *(const s16x8*)&o_buf[((size_t)0*N + rb+rr)*HDc + k0];
      s16x8 u1 = *(const s16x8*)&o_buf[((size_t)1*N + rb+rr)*HDc + k0];
      s16x8 u2 = *(const s16x8*)&o_buf[((size_t)2*N + rb+rr)*HDc + k0];
      FragU fo;
      #pragma unroll
      for (int ii = 0; ii < 4; ++ii){
        float a0 = w0*bf2f((unsigned short)u0[2*ii])   + w1*bf2f((unsigned short)u1[2*ii])   + w2*bf2f((unsigned short)u2[2*ii]);
        float a1 = w0*bf2f((unsigned short)u0[2*ii+1]) + w1*bf2f((unsigned short)u1[2*ii+1]) + w2*bf2f((unsigned short)u2[2*ii+1]);
        fo.u[ii] = cvtpk(a0, a1);
      }
      *(s16x8*)&As[rr*128 + ((kc ^ (rr&7))*8)] = fo.v;
      *(s16x8*)&Bs[rr*128 + ((kc ^ (rr&7))*8)] = *(const s16x8*)&woT_l[(size_t)rr*512 + k0];
    }
    __syncthreads();
    #pragma unroll
    for (int ks = 0; ks < 8; ++ks){
      int s = ks*2 + hi;
      int arow = mt*32 + lo, brow = nt*32 + lo;
      s16x8 af = *(const s16x8*)&As[arow*128 + ((s ^ (arow&7))*8)];
      s16x8 bfr = *(const s16x8*)&Bs[brow*128 + ((s ^ (brow&7))*8)];
      acc = __builtin_amdgcn_mfma_f32_32x32x16_bf16(af, bfr, acc, 0, 0, 0);
    }
  }
  #pragma unroll
  for (int reg = 0; reg < 16; ++reg){
    int m = mt*32 + (reg&3) + 8*(reg>>2) + 4*hi;
    int n = nt*32 + lo;
    cur[(size_t)(rb+m)*64 + n] += acc[reg];
  }
}

// ---------- FFN: cur += relu(LN(cur)@W1+b1)@W2+b2; fused next-layer LN -> xnb ----------
__global__ __launch_bounds__(256) void ffn_kernel(float* __restrict__ cur,
    const float* __restrict__ g, const float* __restrict__ bln,
    const float* __restrict__ W1, const float* __restrict__ b1,
    const float* __restrict__ W2, const float* __restrict__ b2,
    const float* __restrict__ nlg, const float* __restrict__ nlb,
    unsigned short* __restrict__ xnb, int N)
{
  __shared__ __align__(16) float W1s[64][64];
  __shared__ __align__(16) float W2s[64][64];
  __shared__ float xns[4][64];
  __shared__ float t1s[4][64];
  int t = threadIdx.x;
  #pragma unroll
  for (int e = 0; e < 4; ++e){
    int f = t + e*256; int rr = f >> 4, c4 = f & 15;
    *(float4*)&W1s[rr][c4*4] = *(const float4*)&W1[f*4];
    *(float4*)&W2s[rr][c4*4] = *(const float4*)&W2[f*4];
  }
  int w = t >> 6, d = t & 63;
  int row = blockIdx.x*4 + w;
  float v = cur[(size_t)row*64 + d];
  float s = v;
  #pragma unroll
  for (int o = 1; o < 64; o <<= 1) s += __shfl_xor(s, o);
  float mean = s * (1.0f/64.0f);
  float dv = v - mean, sq = dv*dv;
  #pragma unroll
  for (int o = 1; o < 64; o <<= 1) sq += __shfl_xor(sq, o);
  float xnv = dv * rsqrtf(sq*(1.0f/64.0f) + 1e-5f) * g[d] + bln[d];
  xns[w][d] = xnv;
  __syncthreads();
  float acc = b1[d];
  #pragma unroll
  for (int i = 0; i < 64; ++i) acc += xns[w][i]*W1s[i][d];
  t1s[w][d] = fmaxf(acc, 0.f);
  __syncthreads();
  float acc2 = b2[d];
  #pragma unroll
  for (int i = 0; i < 64; ++i) acc2 += t1s[w][i]*W2s[i][d];
  float nv = v + acc2;
  cur[(size_t)row*64 + d] = nv;
  if (nlg){
    float s2 = nv;
    #pragma unroll
    for (int o = 1; o < 64; o <<= 1) s2 += __shfl_xor(s2, o);
    float mean2 = s2 * (1.0f/64.0f);
    float dv2 = nv - mean2, sq2 = dv2*dv2;
    #pragma unroll
    for (int o = 1; o < 64; o <<= 1) sq2 += __shfl_xor(sq2, o);
    xnb[(size_t)row*64 + d] = f2bf(dv2 * rsqrtf(sq2*(1.0f/64.0f) + 1e-5f) * nlg[d] + nlb[d]);
  }
}

// ---------- enc2 (+)= cur @ W_cat[rowoff:rowoff+64, :]  (32 rows/block) ----------
__global__ __launch_bounds__(256) void enc2_accum_kernel(const float* __restrict__ cur,
    const float* __restrict__ Wcat, float* __restrict__ enc2, int rowoff, int store, int N)
{
  __shared__ float Ws[64][33];
  __shared__ float crs[32][65];
  int t = threadIdx.x;
  for (int f = t; f < 2048; f += 256) Ws[f>>5][f&31] = Wcat[(size_t)(rowoff + (f>>5))*32 + (f&31)];
  for (int f = t; f < 2048; f += 256) crs[f>>6][f&63] = cur[(size_t)(blockIdx.x*32 + (f>>6))*64 + (f&63)];
  __syncthreads();
  int r8 = t >> 5, c = t & 31;
  for (int rr = r8; rr < 32; rr += 8){
    int row = blockIdx.x*32 + rr;
    float acc = 0.f;
    #pragma unroll
    for (int d = 0; d < 64; ++d) acc += crs[rr][d]*Ws[d][c];
    size_t o = (size_t)row*32 + c;
    if (store) enc2[o] = acc; else enc2[o] += acc;
  }
}

// ---------- final head ----------
__global__ __launch_bounds__(256) void head_kernel(const float* __restrict__ enc2,
    const float* mW1, const float* mb1, const float* mW2, const float* mb2,
    const float* bW1, const float* bb1, const float* bW2, const float* bb2,
    const float* cW1, const float* cb1, const float* cW2, const float* cb2,
    float* __restrict__ outp, int N)
{
  __shared__ float s_mW1[32][32], s_mW2[32][32], s_bW1[32][16], s_cW1[32][16];
  __shared__ float s_bW2[16], s_cW2[16][3];
  __shared__ float e2[8][32], t1[8][32], ov[8][32], bt[8][16], ct[8][16];
  int t = threadIdx.x;
  for (int f = t; f < 1024; f += 256){ s_mW1[f>>5][f&31] = mW1[f]; s_mW2[f>>5][f&31] = mW2[f]; }
  for (int f = t; f < 512; f += 256){ s_bW1[f>>4][f&15] = bW1[f]; s_cW1[f>>4][f&15] = cW1[f]; }
  if (t < 16) s_bW2[t] = bW2[t];
  if (t < 48) s_cW2[t/3][t%3] = cW2[t];
  int r8 = t >> 5, c = t & 31;
  int row = blockIdx.x*8 + r8;
  float e = enc2[(size_t)row*32 + c];
  e2[r8][c] = e;
  __syncthreads();
  float a = mb1[c];
  #pragma unroll
  for (int i = 0; i < 32; ++i) a += e2[r8][i]*s_mW1[i][c];
  t1[r8][c] = fmaxf(a, 0.f);
  __syncthreads();
  float o = e + mb2[c];
  #pragma unroll
  for (int i = 0; i < 32; ++i) o += t1[r8][i]*s_mW2[i][c];
  ov[r8][c] = o;
  __syncthreads();
  if (c < 16){
    float a2 = bb1[c];
    #pragma unroll
    for (int i = 0; i < 32; ++i) a2 += ov[r8][i]*s_bW1[i][c];
    bt[r8][c] = fmaxf(a2, 0.f);
  } else {
    int cc = c - 16;
    float a2 = cb1[cc];
    #pragma unroll
    for (int i = 0; i < 32; ++i) a2 += ov[r8][i]*s_cW1[i][cc];
    ct[r8][cc] = fmaxf(a2, 0.f);
  }
  __syncthreads();
  if (c == 0){
    float a3 = bb2[0];
    #pragma unroll
    for (int i = 0; i < 16; ++i) a3 += bt[r8][i]*s_bW2[i];
    float sg = 1.0f / (1.0f + __expf(-a3));
    sg = fminf(fmaxf(sg, 1e-6f), 1.0f - 1e-6f);
    outp[row] = sg;
  } else if (c < 4){
    int dd = c - 1;
    float a3 = cb2[dd];
    #pragma unroll
    for (int i = 0; i < 16; ++i) a3 += ct[r8][i]*s_cW2[i][dd];
    outp[(size_t)N + (size_t)row*3 + dd] = a3;
  }
}

// ====================================================================
extern "C" void kernel_launch(void* const* d_in, const int* in_sizes, int n_in,
                              void* d_out, int out_size, void* d_ws, size_t ws_size,
                              hipStream_t stream)
{
  const float* x       = (const float*)d_in[0];
  const float* coords  = (const float*)d_in[1];
  const int*   batch   = (const int*)d_in[2];
  const float* enc_W1  = (const float*)d_in[3];
  const float* enc_b1  = (const float*)d_in[4];
  const float* enc_W2  = (const float*)d_in[5];
  const float* enc_b2  = (const float*)d_in[6];
  const float* ln1_g   = (const float*)d_in[7];
  const float* ln1_b   = (const float*)d_in[8];
  const float* wq      = (const float*)d_in[9];
  const float* wk      = (const float*)d_in[10];
  const float* wv      = (const float*)d_in[11];
  const float* rpe_W   = (const float*)d_in[12];
  const float* wo      = (const float*)d_in[13];
  const float* ln2_g   = (const float*)d_in[14];
  const float* ln2_b   = (const float*)d_in[15];
  const float* ff_W1   = (const float*)d_in[16];
  const float* ff_b1   = (const float*)d_in[17];
  const float* ff_W2   = (const float*)d_in[18];
  const float* ff_b2   = (const float*)d_in[19];
  const float* W_cat   = (const float*)d_in[20];
  const float* mlp_W1  = (const float*)d_in[21];
  const float* mlp_b1  = (const float*)d_in[22];
  const float* mlp_W2  = (const float*)d_in[23];
  const float* mlp_b2  = (const float*)d_in[24];
  const float* beta_W1 = (const float*)d_in[25];
  const float* beta_b1 = (const float*)d_in[26];
  const float* beta_W2 = (const float*)d_in[27];
  const float* beta_b2 = (const float*)d_in[28];
  const float* coord_W1= (const float*)d_in[29];
  const float* coord_b1= (const float*)d_in[30];
  const float* coord_W2= (const float*)d_in[31];
  const float* coord_b2= (const float*)d_in[32];
  const float* hash_proj=(const float*)d_in[33];

  const int N  = in_sizes[0] / 16;
  const int nb = N / 128;
  float* outp = (float*)d_out;
  (void)out_size; (void)ws_size; (void)n_in;

  char* p = (char*)d_ws;
  size_t off = 0;
  auto alloc = [&](size_t bytes) -> char* {
    char* r = p + off;
    off += (bytes + 255) & ~(size_t)255;
    return r;
  };
  float* cur    = (float*)alloc((size_t)N*64*4);
  unsigned short* xnb = (unsigned short*)alloc((size_t)N*64*2);
  unsigned short* q = (unsigned short*)alloc((size_t)N*512*2);
  unsigned short* k = (unsigned short*)alloc((size_t)N*512*2);
  unsigned short* v = (unsigned short*)alloc((size_t)N*512*2);
  unsigned short* o_buf = (unsigned short*)alloc((size_t)3*N*512*2);
  float* enc2   = (float*)alloc((size_t)N*32*4);
  float* lse    = (float*)alloc((size_t)3*N*8*4);
  unsigned long long* keys = (unsigned long long*)alloc((size_t)3*N*8);
  int* idx      = (int*)alloc((size_t)3*N*4);
  unsigned short* wqkvT = (unsigned short*)alloc((size_t)4*3*512*64*2);
  unsigned short* woT   = (unsigned short*)alloc((size_t)4*64*512*2);
  unsigned* mm  = (unsigned*)alloc(256);
  float* whead  = (float*)alloc(256);

  // ---- weight convert/transpose + whead (all layers, once) ----
  wconv_kernel<<<2048, 256, 0, stream>>>(wq, wk, wv, wo, wqkvT, woT);
  whead_kernel<<<32, 64, 0, stream>>>(rpe_W, whead);

  // ---- sort keys (3 hash rounds, once) ----
  minmax_init_kernel<<<1, 64, 0, stream>>>(mm);
  minmax_reduce_kernel<<<64, 256, 0, stream>>>(coords, hash_proj, mm, N);
  make_keys_kernel<<<(N+255)/256, 256, 0, stream>>>(coords, batch, hash_proj, mm, keys, N);
  bitonic_local_full8k_kernel<<<dim3(N/8192, 3), 1024, 0, stream>>>(keys, N);
  for (int kk = 16384; kk <= N; kk <<= 1){
    for (int j = kk >> 1; j >= 8192; j >>= 1)
      bitonic_global_kernel<<<dim3(N/256, 3), 256, 0, stream>>>(keys, N, kk, j);
    bitonic_local_merge8k_kernel<<<dim3(N/8192, 3), 1024, 0, stream>>>(keys, N, kk);
  }
  extract_idx_kernel<<<(3*N+255)/256, 256, 0, stream>>>(keys, idx, 3*N);

  // ---- encoder (+ fused layer-0 LN) + feats[0] contribution to enc2 ----
  encoder_kernel<<<N/4, 256, 0, stream>>>(x, enc_W1, enc_b1, enc_W2, enc_b2,
      ln1_g, ln1_b, cur, xnb, N);
  enc2_accum_kernel<<<N/32, 256, 0, stream>>>(cur, W_cat, enc2, 0, 1, N);

  // ---- layers ----
  for (int l = 0; l < 4; ++l){
    qkv_mfma_kernel<<<dim3(N/128, 4, 3), 256, 0, stream>>>(xnb,
        wqkvT + (size_t)l*3*512*64, q, k, v, N);
    attn_kernel<<<dim3(nb, 8, 3), 256, 0, stream>>>(q, k, v, coords, batch,
        idx, whead + l*8, lse, o_buf, N);
    wo_mfma_kernel<<<N/64, 256, 0, stream>>>(o_buf, lse, woT + (size_t)l*64*512, cur, N);
    const float* nlg = (l < 3) ? (ln1_g + (l+1)*64) : nullptr;
    const float* nlb = (l < 3) ? (ln1_b + (l+1)*64) : nullptr;
    ffn_kernel<<<N/4, 256, 0, stream>>>(cur, ln2_g + l*64, ln2_b + l*64,
        ff_W1 + (size_t)l*64*64, ff_b1 + l*64, ff_W2 + (size_t)l*64*64, ff_b2 + l*64,
        nlg, nlb, xnb, N);
    enc2_accum_kernel<<<N/32, 256, 0, stream>>>(cur, W_cat, enc2, (l+1)*64, 0, N);
  }

  // ---- head ----
  head_kernel<<<N/8, 256, 0, stream>>>(enc2, mlp_W1, mlp_b1, mlp_W2, mlp_b2,
      beta_W1, beta_b1, beta_W2, beta_b2, coord_W1, coord_b1, coord_W2, coord_b2, outp, N);
}

// Round 8
// 787.684 us; speedup vs baseline: 1.0658x; 1.0658x over previous
//
#include <hip/hip_runtime.h>
#include <math.h>

#define DEV __device__ __forceinline__

constexpr int DHc = 64;
constexpr int HDc = 512;
constexpr int Hc  = 8;
constexpr int BLKc = 128;

typedef float f32x16 __attribute__((ext_vector_type(16)));
typedef short s16x8  __attribute__((ext_vector_type(8)));

union FragU { unsigned u[4]; s16x8 v; };

// ---------- float <-> order-preserving uint ----------
DEV unsigned fenc(float f){ unsigned u = __float_as_uint(f); return (u & 0x80000000u) ? ~u : (u | 0x80000000u); }
DEV float fdec(unsigned u){ unsigned b = (u & 0x80000000u) ? (u ^ 0x80000000u) : ~u; return __uint_as_float(b); }
DEV float hv_calc(float c0, float c1, float h0, float h1){
  return __fadd_rn(__fmul_rn(c0, h0), __fmul_rn(c1, h1));
}
// bf16 encode (round-to-nearest-even) / decode
DEV unsigned short f2bf(float f){
  unsigned u = __float_as_uint(f);
  return (unsigned short)((u + 0x7FFFu + ((u >> 16) & 1u)) >> 16);
}
DEV float bf2f(unsigned short s){ return __uint_as_float((unsigned)s << 16); }

// pack two f32 -> bf16x2 (RNE), src0 -> low half
DEV unsigned cvtpk(float lo, float hi){
  unsigned r;
  asm("v_cvt_pk_bf16_f32 %0, %1, %2" : "=v"(r) : "v"(lo), "v"(hi));
  return r;
}
// explicit-RNE pack (used for V: rounding mode guaranteed)
DEV unsigned pack_bf2(float lo, float hi){
  return (unsigned)f2bf(lo) | ((unsigned)f2bf(hi) << 16);
}
// v_permlane32_swap_b32
DEV void pswap(unsigned &a, unsigned &b){
  asm volatile("v_permlane32_swap_b32 %0, %1" : "+v"(a), "+v"(b));
}

// ---------- min/max reductions for sort keys ----------
__global__ void minmax_init_kernel(unsigned* mm){
  int t = threadIdx.x;
  if (t < 4) mm[t] = 0xFFFFFFFFu;
  else if (t < 8) mm[t] = 0u;
}

__global__ __launch_bounds__(256) void minmax_reduce_kernel(const float* __restrict__ coords,
    const float* __restrict__ hp, unsigned* mm, int N)
{
  __shared__ float red[4][8];
  float h[6];
  #pragma unroll
  for (int i = 0; i < 6; ++i) h[i] = hp[i];
  float mn[4] = {3.0e38f, 3.0e38f, 3.0e38f, 3.0e38f};
  float mx[4] = {-3.0e38f, -3.0e38f, -3.0e38f, -3.0e38f};
  for (int i = blockIdx.x*blockDim.x + threadIdx.x; i < N; i += gridDim.x*blockDim.x){
    float2 c = *(const float2*)&coords[2*i];
    float v0 = c.x;
    float v1 = hv_calc(c.x, c.y, h[0], h[1]);
    float v2 = hv_calc(c.x, c.y, h[2], h[3]);
    float v3 = hv_calc(c.x, c.y, h[4], h[5]);
    mn[0] = fminf(mn[0], v0); mx[0] = fmaxf(mx[0], v0);
    mn[1] = fminf(mn[1], v1); mx[1] = fmaxf(mx[1], v1);
    mn[2] = fminf(mn[2], v2); mx[2] = fmaxf(mx[2], v2);
    mn[3] = fminf(mn[3], v3); mx[3] = fmaxf(mx[3], v3);
  }
  #pragma unroll
  for (int o = 1; o < 64; o <<= 1){
    #pragma unroll
    for (int s = 0; s < 4; ++s){
      mn[s] = fminf(mn[s], __shfl_xor(mn[s], o));
      mx[s] = fmaxf(mx[s], __shfl_xor(mx[s], o));
    }
  }
  int w = threadIdx.x >> 6;
  if ((threadIdx.x & 63) == 0){
    #pragma unroll
    for (int s = 0; s < 4; ++s){ red[w][s] = mn[s]; red[w][4+s] = mx[s]; }
  }
  __syncthreads();
  int t = threadIdx.x;
  if (t < 4){
    float v = fminf(fminf(red[0][t], red[1][t]), fminf(red[2][t], red[3][t]));
    atomicMin(&mm[t], fenc(v));
  } else if (t < 8){
    float v = fmaxf(fmaxf(red[0][t], red[1][t]), fmaxf(red[2][t], red[3][t]));
    atomicMax(&mm[t], fenc(v));
  }
}

__global__ void make_keys_kernel(const float* __restrict__ coords, const int* __restrict__ batch,
                                 const float* __restrict__ hp, const unsigned* __restrict__ mm,
                                 unsigned long long* __restrict__ keys, int N)
{
  int i = blockIdx.x*blockDim.x + threadIdx.x;
  if (i >= N) return;
  float c0 = coords[2*i], c1 = coords[2*i+1];
  float c0min = fdec(mm[0]), c0max = fdec(mm[4]);
  float rf = (c0 - c0min) / (c0max - c0min + 1e-6f) * 8.0f;
  int region = (int)rf;
  region = region < 0 ? 0 : (region > 7 ? 7 : region);
  float base2 = ((float)batch[i] * 8.0f + (float)region) * 2.0f;
  #pragma unroll
  for (int r = 0; r < 3; ++r){
    float hv = hv_calc(c0, c1, hp[2*r], hp[2*r+1]);
    float hn = (hv - fdec(mm[1+r])) / (fdec(mm[5+r]) - fdec(mm[1+r]) + 1e-6f);
    float skey = base2 + hn;
    keys[(size_t)r*N + i] = ((unsigned long long)__float_as_uint(skey) << 32) | (unsigned)i;
  }
}

// ---------- bitonic sort, 2048-element local tiles (thread-per-pair) ----------
__global__ __launch_bounds__(1024) void bitonic_local_full2k_kernel(unsigned long long* keys, int N)
{
  __shared__ unsigned long long sh[2048];
  unsigned long long* a = keys + (size_t)blockIdx.y * N;
  int base = blockIdx.x * 2048, t = threadIdx.x;
  sh[t] = a[base + t];
  sh[t + 1024] = a[base + t + 1024];
  __syncthreads();
  for (int k = 2; k <= 2048; k <<= 1){
    for (int j = k >> 1; j > 0; j >>= 1){
      int i = ((t & ~(j-1)) << 1) | (t & (j-1));
      bool dirup = (((base + i) & k) == 0);
      unsigned long long x = sh[i], y = sh[i+j];
      if ((x > y) == dirup){ sh[i] = y; sh[i+j] = x; }
      __syncthreads();
    }
  }
  a[base + t] = sh[t];
  a[base + t + 1024] = sh[t + 1024];
}

__global__ void bitonic_global_kernel(unsigned long long* keys, int N, int k, int j)
{
  unsigned long long* a = keys + (size_t)blockIdx.y * N;
  int i = blockIdx.x*blockDim.x + threadIdx.x;
  int l = i ^ j;
  if (l > i && l < N){
    unsigned long long x = a[i], y = a[l];
    bool dirup = ((i & k) == 0);
    if ((x > y) == dirup){ a[i] = y; a[l] = x; }
  }
}

__global__ __launch_bounds__(1024) void bitonic_local_merge2k_kernel(unsigned long long* keys, int N, int k)
{
  __shared__ unsigned long long sh[2048];
  unsigned long long* a = keys + (size_t)blockIdx.y * N;
  int base = blockIdx.x * 2048, t = threadIdx.x;
  sh[t] = a[base + t];
  sh[t + 1024] = a[base + t + 1024];
  __syncthreads();
  for (int j = 1024; j > 0; j >>= 1){
    int i = ((t & ~(j-1)) << 1) | (t & (j-1));
    bool dirup = (((base + i) & k) == 0);
    unsigned long long x = sh[i], y = sh[i+j];
    if ((x > y) == dirup){ sh[i] = y; sh[i+j] = x; }
    __syncthreads();
  }
  a[base + t] = sh[t];
  a[base + t + 1024] = sh[t + 1024];
}

__global__ void extract_idx_kernel(const unsigned long long* __restrict__ keys, int* __restrict__ idx, int total)
{
  int i = blockIdx.x*blockDim.x + threadIdx.x;
  if (i < total) idx[i] = (int)(keys[i] & 0xFFFFFFFFull);
}

// ---------- weight convert+transpose (once): wqkvT[l][z][n][k] (q pre-scaled 0.125 exact), woT[l][n][k] ----------
__global__ void wconv_kernel(const float* __restrict__ wq, const float* __restrict__ wk,
                             const float* __restrict__ wv, const float* __restrict__ wo,
                             unsigned short* __restrict__ wqkvT, unsigned short* __restrict__ woT)
{
  int tid = blockIdx.x*blockDim.x + threadIdx.x;
  const int NQ = 4*3*512*64;
  if (tid < NQ){
    int kk = tid & 63;
    int rest = tid >> 6;
    int n = rest & 511;
    int rest2 = rest >> 9;
    int z = rest2 % 3, l = rest2 / 3;
    const float* W = (z==0) ? wq : (z==1) ? wk : wv;
    float scale = (z==0) ? 0.125f : 1.0f;   // exact pow-2 scale: f2bf(W*0.125) == f2bf(W) * 0.125
    wqkvT[tid] = f2bf(W[((size_t)l*64 + kk)*512 + n] * scale);
  } else if (tid < NQ + 4*64*512){
    int e = tid - NQ;
    int kk = e & 511;
    int rest = e >> 9;
    int n = rest & 63;
    int l = rest >> 6;
    woT[e] = f2bf(wo[((size_t)l*512 + kk)*64 + n]);
  }
}

// ---------- encoder: h0 = relu(x@W1+b1)@W2+b2; fused LN(layer0) -> xnb ----------
__global__ __launch_bounds__(256) void encoder_kernel(const float* __restrict__ x,
    const float* __restrict__ W1, const float* __restrict__ b1,
    const float* __restrict__ W2, const float* __restrict__ b2,
    const float* __restrict__ lng, const float* __restrict__ lnb,
    float* __restrict__ h0, unsigned short* __restrict__ xnb, int N)
{
  __shared__ float W1s[16][64];
  __shared__ __align__(16) float W2s[64][64];
  __shared__ float xs[4][16];
  __shared__ float t1s[4][64];
  int t = threadIdx.x;
  for (int f = t; f < 1024; f += 256) W1s[f>>6][f&63] = W1[f];
  #pragma unroll
  for (int e = 0; e < 4; ++e){ int f = t + e*256; *(float4*)&W2s[f>>4][(f&15)*4] = *(const float4*)&W2[f*4]; }
  int w = t >> 6, d = t & 63;
  int row = blockIdx.x*4 + w;
  if (d < 16) xs[w][d] = x[(size_t)row*16 + d];
  __syncthreads();
  float acc = b1[d];
  #pragma unroll
  for (int i = 0; i < 16; ++i) acc += xs[w][i]*W1s[i][d];
  t1s[w][d] = fmaxf(acc, 0.f);
  __syncthreads();
  float acc2 = b2[d];
  #pragma unroll
  for (int i = 0; i < 64; ++i) acc2 += t1s[w][i]*W2s[i][d];
  h0[(size_t)row*64 + d] = acc2;
  // fused LN for layer 0
  float s = acc2;
  #pragma unroll
  for (int o = 1; o < 64; o <<= 1) s += __shfl_xor(s, o);
  float mean = s * (1.0f/64.0f);
  float dv = acc2 - mean, sq = dv*dv;
  #pragma unroll
  for (int o = 1; o < 64; o <<= 1) sq += __shfl_xor(sq, o);
  xnb[(size_t)row*64 + d] = f2bf(dv * rsqrtf(sq*(1.0f/64.0f) + 1e-5f) * lng[d] + lnb[d]);
}

// ---------- w_head (all 4 layers, once) ----------
__global__ void whead_kernel(const float* __restrict__ rpe, float* __restrict__ wh)
{
  int l = blockIdx.x >> 3, h = blockIdx.x & 7, d = threadIdx.x;
  const float* rp = rpe + (size_t)l*8*512;
  float s = 0.f;
  #pragma unroll
  for (int w = 0; w < 8; ++w) s += rp[(size_t)w*512 + h*64 + d];
  #pragma unroll
  for (int o = 1; o < 64; o <<= 1) s += __shfl_xor(s, o);
  if (d == 0){
    float m = s * (1.0f/512.0f);
    wh[blockIdx.x] = fmaxf(m, 0.f) + log1pf(expf(-fabsf(m)));
  }
}

// ============ fused QKV + single-pass MFMA attention ============
// per (block b, head h, round r): gather 128 sorted xnb rows; compute Q/K/V
// head-slices via MFMA (A gathered from global, W^T streamed from global);
// write to the verified swizzled LDS layouts; then verified QK^T/softmax/PV.
__global__ __launch_bounds__(256, 3) void attn_kernel(
    const unsigned short* __restrict__ xnb, const unsigned short* __restrict__ wqkvT_l,
    const float* __restrict__ coords, const int* __restrict__ batch,
    const int* __restrict__ idx_all, const float* __restrict__ w_head,
    float* __restrict__ lse_all, unsigned short* __restrict__ o_buf, int N)
{
  __shared__ __align__(16) unsigned short qlds[128*64];
  __shared__ __align__(16) unsigned short klds[128*64];
  __shared__ __align__(16) unsigned short vtl[64*128];   // V^T [d][k]
  __shared__ __align__(16) float c1s[BLKc];
  __shared__ __align__(16) int   bts[BLKc];
  __shared__ int   idxs[BLKc];
  __shared__ __align__(16) float isel[BLKc];
  __shared__ int unif;
  int b = blockIdx.x, h = blockIdx.y, r = blockIdx.z, t = threadIdx.x;
  const int* idx_r = idx_all + (size_t)r*N;
  if (t < BLKc){
    int g = idx_r[b*BLKc + t];
    idxs[t] = g; c1s[t] = coords[2*g+1]; bts[t] = batch[g];
  }
  __syncthreads();
  if (t == 0) unif = (bts[0] == bts[127]);

  int w = t >> 6, l = t & 63, lo = l & 31, hi = l >> 5;

  // ---- gather this wave's A-frags (sorted xnb rows w*32..w*32+31) ----
  int gm = idxs[w*32 + lo];
  const unsigned short* arp = &xnb[(size_t)gm*64];
  s16x8 af[4];
  #pragma unroll
  for (int ks = 0; ks < 4; ++ks)
    af[ks] = *(const s16x8*)&arp[ks*16 + hi*8];

  // ---- per-z GEMM: Q,K -> swizzled [row][d] lds; V -> vtl [d][k] ----
  const unsigned short* whb = wqkvT_l + (size_t)h*64*64;
  #pragma unroll
  for (int z = 0; z < 3; ++z){
    const unsigned short* wz = whb + (size_t)z*512*64;
    f32x16 a0, a1;
    #pragma unroll
    for (int i = 0; i < 16; ++i){ a0[i] = 0.f; a1[i] = 0.f; }
    #pragma unroll
    for (int ks = 0; ks < 4; ++ks){
      s16x8 b0 = *(const s16x8*)&wz[(size_t)(lo)*64      + ks*16 + hi*8];
      s16x8 b1 = *(const s16x8*)&wz[(size_t)(32 + lo)*64 + ks*16 + hi*8];
      a0 = __builtin_amdgcn_mfma_f32_32x32x16_bf16(af[ks], b0, a0, 0, 0, 0);
      a1 = __builtin_amdgcn_mfma_f32_32x32x16_bf16(af[ks], b1, a1, 0, 0, 0);
    }
    if (z < 2){
      unsigned short* dst = z ? klds : qlds;
      int ch0 = lo >> 3, ch1 = 4 + (lo >> 3), co = lo & 7;
      #pragma unroll
      for (int reg = 0; reg < 16; ++reg){
        int row = w*32 + (reg&3) + 8*(reg>>2) + 4*hi;
        dst[row*64 + ((ch0 ^ (row&7))*8) + co] = f2bf(a0[reg]);
        dst[row*64 + ((ch1 ^ (row&7))*8) + co] = f2bf(a1[reg]);
      }
    } else {
      #pragma unroll
      for (int rq = 0; rq < 4; ++rq){
        int k0 = w*32 + rq*8 + 4*hi;
        int cj = k0 >> 3;
        int d0 = lo, d1 = 32 + lo;
        unsigned* dp0 = (unsigned*)&vtl[d0*128 + ((cj ^ (d0&7))*8) + 4*hi];
        dp0[0] = pack_bf2(a0[rq*4+0], a0[rq*4+1]);
        dp0[1] = pack_bf2(a0[rq*4+2], a0[rq*4+3]);
        unsigned* dp1 = (unsigned*)&vtl[d1*128 + ((cj ^ (d1&7))*8) + 4*hi];
        dp1[0] = pack_bf2(a1[rq*4+0], a1[rq*4+1]);
        dp1[1] = pack_bf2(a1[rq*4+2], a1[rq*4+3]);
      }
    }
  }
  __syncthreads();

  int qrow = w*32 + lo;
  s16x8 qf[4];
  #pragma unroll
  for (int ks = 0; ks < 4; ++ks)
    qf[ks] = *(const s16x8*)&qlds[qrow*64 + ((((ks<<1)|hi) ^ (qrow&7))*8)];

  f32x16 acc[4];
  #pragma unroll
  for (int kt = 0; kt < 4; ++kt)
    #pragma unroll
    for (int i = 0; i < 16; ++i) acc[kt][i] = 0.f;

  __builtin_amdgcn_s_setprio(1);
  #pragma unroll
  for (int kt = 0; kt < 4; ++kt){
    int krow = kt*32 + lo;
    #pragma unroll
    for (int ks = 0; ks < 4; ++ks){
      s16x8 kf = *(const s16x8*)&klds[krow*64 + ((((ks<<1)|hi) ^ (krow&7))*8)];
      acc[kt] = __builtin_amdgcn_mfma_f32_32x32x16_bf16(kf, qf[ks], acc[kt], 0, 0, 0);
    }
  }
  __builtin_amdgcn_s_setprio(0);

  float c1i = c1s[qrow]; int bti = bts[qrow];
  float wh = w_head[h];
  int msk = unif;
  // scores: rpe + (conditional) batch mask; q pre-scaled so no *0.125 here
  #pragma unroll
  for (int kt = 0; kt < 4; ++kt){
    #pragma unroll
    for (int rq = 0; rq < 4; ++rq){
      int kb = kt*32 + rq*8 + hi*4;
      float4 c4 = *(const float4*)&c1s[kb];
      int4  b4 = *(const int4*)&bts[kb];
      #pragma unroll
      for (int j = 0; j < 4; ++j){
        int reg = rq*4 + j;
        float c1k = (j==0)?c4.x:(j==1)?c4.y:(j==2)?c4.z:c4.w;
        int   btk = (j==0)?b4.x:(j==1)?b4.y:(j==2)?b4.z:b4.w;
        float dd = c1i - c1k;
        float sc = acc[kt][reg] - wh*dd*dd;
        if (!msk && bti != btk) sc = -1e9f;
        acc[kt][reg] = sc;
      }
    }
  }

  // full-row softmax (row split across lane pair l, l^32)
  float m = -3.0e38f;
  #pragma unroll
  for (int kt = 0; kt < 4; ++kt)
    #pragma unroll
    for (int i = 0; i < 16; ++i) m = fmaxf(m, acc[kt][i]);
  m = fmaxf(m, __shfl_xor(m, 32));
  float se = 0.f;
  #pragma unroll
  for (int kt = 0; kt < 4; ++kt)
    #pragma unroll
    for (int i = 0; i < 16; ++i){
      float p = __expf(acc[kt][i] - m);
      acc[kt][i] = p;
      se += p;
    }
  se += __shfl_xor(se, 32);
  if (l < 32){
    int gi0 = idxs[qrow];
    lse_all[((size_t)r*N + gi0)*Hc + h] = m + __logf(se);
    isel[qrow] = 1.0f / se;
  }

  // PV via in-register bf16 pack (cvt_pk + permlane32_swap)
  f32x16 oa0, oa1;
  #pragma unroll
  for (int i = 0; i < 16; ++i){ oa0[i] = 0.f; oa1[i] = 0.f; }

  __builtin_amdgcn_s_setprio(1);
  #pragma unroll
  for (int kt = 0; kt < 4; ++kt){
    unsigned X = cvtpk(acc[kt][0],  acc[kt][1]);
    unsigned Z = cvtpk(acc[kt][2],  acc[kt][3]);
    unsigned Y = cvtpk(acc[kt][4],  acc[kt][5]);
    unsigned W = cvtpk(acc[kt][6],  acc[kt][7]);
    pswap(X, Y); pswap(Z, W);
    FragU f0; f0.u[0]=X; f0.u[1]=Z; f0.u[2]=Y; f0.u[3]=W;
    unsigned X2 = cvtpk(acc[kt][8],  acc[kt][9]);
    unsigned Z2 = cvtpk(acc[kt][10], acc[kt][11]);
    unsigned Y2 = cvtpk(acc[kt][12], acc[kt][13]);
    unsigned W2 = cvtpk(acc[kt][14], acc[kt][15]);
    pswap(X2, Y2); pswap(Z2, W2);
    FragU f1; f1.u[0]=X2; f1.u[1]=Z2; f1.u[2]=Y2; f1.u[3]=W2;
    #pragma unroll
    for (int hks = 0; hks < 2; ++hks){
      s16x8 pa = hks ? f1.v : f0.v;
      int kch = kt*4 + hks*2 + hi;
      int d0 = lo;
      s16x8 vf0 = *(const s16x8*)&vtl[d0*128 + ((kch ^ (d0&7))*8)];
      oa0 = __builtin_amdgcn_mfma_f32_32x32x16_bf16(pa, vf0, oa0, 0, 0, 0);
      int d1 = 32 + lo;
      s16x8 vf1 = *(const s16x8*)&vtl[d1*128 + ((kch ^ (d1&7))*8)];
      oa1 = __builtin_amdgcn_mfma_f32_32x32x16_bf16(pa, vf1, oa1, 0, 0, 0);
    }
  }
  __builtin_amdgcn_s_setprio(0);

  // epilogue: o_r[g][h*64 + d] = bf16(O / se)
  unsigned short* orow = o_buf + (size_t)r*N*HDc;
  #pragma unroll
  for (int rq = 0; rq < 4; ++rq){
    float4 s4 = *(const float4*)&isel[w*32 + rq*8 + hi*4];
    #pragma unroll
    for (int j = 0; j < 4; ++j){
      int reg = rq*4 + j;
      int qq = rq*8 + hi*4 + j;
      int g = idxs[w*32 + qq];
      float sv = (j==0)?s4.x:(j==1)?s4.y:(j==2)?s4.z:s4.w;
      unsigned short* dst = &orow[(size_t)g*HDc + h*DHc + lo];
      dst[0]  = f2bf(oa0[reg]*sv);
      dst[32] = f2bf(oa1[reg]*sv);
    }
  }
  (void)b;
}

// ---------- WO MFMA with fused cross-round combine ----------
__global__ __launch_bounds__(256) void wo_mfma_kernel(
    const unsigned short* __restrict__ o_buf, const float* __restrict__ lse_all,
    const unsigned short* __restrict__ woT_l, float* __restrict__ cur, int N)
{
  __shared__ __align__(16) unsigned short As[64*128];
  __shared__ __align__(16) unsigned short Bs[64*128];
  __shared__ float wts[64][24];
  int rb = blockIdx.x*64, t = threadIdx.x;
  #pragma unroll
  for (int e = 0; e < 2; ++e){
    int p = t + e*256;
    int rr = p >> 3, h = p & 7;
    float l0 = lse_all[((size_t)0*N + rb+rr)*Hc + h];
    float l1 = lse_all[((size_t)1*N + rb+rr)*Hc + h];
    float l2 = lse_all[((size_t)2*N + rb+rr)*Hc + h];
    float lm = fmaxf(l0, fmaxf(l1, l2));
    float e0 = __expf(l0-lm), e1 = __expf(l1-lm), e2 = __expf(l2-lm);
    float inv = 1.0f/(e0+e1+e2);
    wts[rr][h*3+0] = e0*inv; wts[rr][h*3+1] = e1*inv; wts[rr][h*3+2] = e2*inv;
  }
  int w = t >> 6, l = t & 63, lo = l & 31, hi = l >> 5;
  int mt = w >> 1, nt = w & 1;
  f32x16 acc;
  #pragma unroll
  for (int i = 0; i < 16; ++i) acc[i] = 0.f;
  for (int kt = 0; kt < 4; ++kt){
    __syncthreads();
    #pragma unroll
    for (int e = 0; e < 4; ++e){
      int f = t + e*256; int rr = f >> 4, kc = f & 15;
      int k0 = kt*128 + kc*8;
      int h = k0 >> 6;
      float w0 = wts[rr][h*3+0], w1 = wts[rr][h*3+1], w2 = wts[rr][h*3+2];
      s16x8 u0 = *(const s16x8*)&o_buf[((size_t)0*N + rb+rr)*HDc + k0];
      s16x8 u1 = *(const s16x8*)&o_buf[((size_t)1*N + rb+rr)*HDc + k0];
      s16x8 u2 = *(const s16x8*)&o_buf[((size_t)2*N + rb+rr)*HDc + k0];
      FragU fo;
      #pragma unroll
      for (int ii = 0; ii < 4; ++ii){
        float a0 = w0*bf2f((unsigned short)u0[2*ii])   + w1*bf2f((unsigned short)u1[2*ii])   + w2*bf2f((unsigned short)u2[2*ii]);
        float a1 = w0*bf2f((unsigned short)u0[2*ii+1]) + w1*bf2f((unsigned short)u1[2*ii+1]) + w2*bf2f((unsigned short)u2[2*ii+1]);
        fo.u[ii] = cvtpk(a0, a1);
      }
      *(s16x8*)&As[rr*128 + ((kc ^ (rr&7))*8)] = fo.v;
      *(s16x8*)&Bs[rr*128 + ((kc ^ (rr&7))*8)] = *(const s16x8*)&woT_l[(size_t)rr*512 + k0];
    }
    __syncthreads();
    #pragma unroll
    for (int ks = 0; ks < 8; ++ks){
      int s = ks*2 + hi;
      int arow = mt*32 + lo, brow = nt*32 + lo;
      s16x8 af = *(const s16x8*)&As[arow*128 + ((s ^ (arow&7))*8)];
      s16x8 bfr = *(const s16x8*)&Bs[brow*128 + ((s ^ (brow&7))*8)];
      acc = __builtin_amdgcn_mfma_f32_32x32x16_bf16(af, bfr, acc, 0, 0, 0);
    }
  }
  #pragma unroll
  for (int reg = 0; reg < 16; ++reg){
    int m = mt*32 + (reg&3) + 8*(reg>>2) + 4*hi;
    int n = nt*32 + lo;
    cur[(size_t)(rb+m)*64 + n] += acc[reg];
  }
}

// ---------- FFN: cur += relu(LN(cur)@W1+b1)@W2+b2; fused next-layer LN -> xnb ----------
__global__ __launch_bounds__(256) void ffn_kernel(float* __restrict__ cur,
    const float* __restrict__ g, const float* __restrict__ bln,
    const float* __restrict__ W1, const float* __restrict__ b1,
    const float* __restrict__ W2, const float* __restrict__ b2,
    const float* __restrict__ nlg, const float* __restrict__ nlb,
    unsigned short* __restrict__ xnb, int N)
{
  __shared__ __align__(16) float W1s[64][64];
  __shared__ __align__(16) float W2s[64][64];
  __shared__ float xns[4][64];
  __shared__ float t1s[4][64];
  int t = threadIdx.x;
  #pragma unroll
  for (int e = 0; e < 4; ++e){
    int f = t + e*256; int rr = f >> 4, c4 = f & 15;
    *(float4*)&W1s[rr][c4*4] = *(const float4*)&W1[f*4];
    *(float4*)&W2s[rr][c4*4] = *(const float4*)&W2[f*4];
  }
  int w = t >> 6, d = t & 63;
  int row = blockIdx.x*4 + w;
  float v = cur[(size_t)row*64 + d];
  float s = v;
  #pragma unroll
  for (int o = 1; o < 64; o <<= 1) s += __shfl_xor(s, o);
  float mean = s * (1.0f/64.0f);
  float dv = v - mean, sq = dv*dv;
  #pragma unroll
  for (int o = 1; o < 64; o <<= 1) sq += __shfl_xor(sq, o);
  float xnv = dv * rsqrtf(sq*(1.0f/64.0f) + 1e-5f) * g[d] + bln[d];
  xns[w][d] = xnv;
  __syncthreads();
  float acc = b1[d];
  #pragma unroll
  for (int i = 0; i < 64; ++i) acc += xns[w][i]*W1s[i][d];
  t1s[w][d] = fmaxf(acc, 0.f);
  __syncthreads();
  float acc2 = b2[d];
  #pragma unroll
  for (int i = 0; i < 64; ++i) acc2 += t1s[w][i]*W2s[i][d];
  float nv = v + acc2;
  cur[(size_t)row*64 + d] = nv;
  if (nlg){
    float s2 = nv;
    #pragma unroll
    for (int o = 1; o < 64; o <<= 1) s2 += __shfl_xor(s2, o);
    float mean2 = s2 * (1.0f/64.0f);
    float dv2 = nv - mean2, sq2 = dv2*dv2;
    #pragma unroll
    for (int o = 1; o < 64; o <<= 1) sq2 += __shfl_xor(sq2, o);
    xnb[(size_t)row*64 + d] = f2bf(dv2 * rsqrtf(sq2*(1.0f/64.0f) + 1e-5f) * nlg[d] + nlb[d]);
  }
}

// ---------- enc2 (+)= cur @ W_cat[rowoff:rowoff+64, :]  (32 rows/block) ----------
__global__ __launch_bounds__(256) void enc2_accum_kernel(const float* __restrict__ cur,
    const float* __restrict__ Wcat, float* __restrict__ enc2, int rowoff, int store, int N)
{
  __shared__ float Ws[64][33];
  __shared__ float crs[32][65];
  int t = threadIdx.x;
  for (int f = t; f < 2048; f += 256) Ws[f>>5][f&31] = Wcat[(size_t)(rowoff + (f>>5))*32 + (f&31)];
  for (int f = t; f < 2048; f += 256) crs[f>>6][f&63] = cur[(size_t)(blockIdx.x*32 + (f>>6))*64 + (f&63)];
  __syncthreads();
  int r8 = t >> 5, c = t & 31;
  for (int rr = r8; rr < 32; rr += 8){
    int row = blockIdx.x*32 + rr;
    float acc = 0.f;
    #pragma unroll
    for (int d = 0; d < 64; ++d) acc += crs[rr][d]*Ws[d][c];
    size_t o = (size_t)row*32 + c;
    if (store) enc2[o] = acc; else enc2[o] += acc;
  }
}

// ---------- final head ----------
__global__ __launch_bounds__(256) void head_kernel(const float* __restrict__ enc2,
    const float* mW1, const float* mb1, const float* mW2, const float* mb2,
    const float* bW1, const float* bb1, const float* bW2, const float* bb2,
    const float* cW1, const float* cb1, const float* cW2, const float* cb2,
    float* __restrict__ outp, int N)
{
  __shared__ float s_mW1[32][32], s_mW2[32][32], s_bW1[32][16], s_cW1[32][16];
  __shared__ float s_bW2[16], s_cW2[16][3];
  __shared__ float e2[8][32], t1[8][32], ov[8][32], bt[8][16], ct[8][16];
  int t = threadIdx.x;
  for (int f = t; f < 1024; f += 256){ s_mW1[f>>5][f&31] = mW1[f]; s_mW2[f>>5][f&31] = mW2[f]; }
  for (int f = t; f < 512; f += 256){ s_bW1[f>>4][f&15] = bW1[f]; s_cW1[f>>4][f&15] = cW1[f]; }
  if (t < 16) s_bW2[t] = bW2[t];
  if (t < 48) s_cW2[t/3][t%3] = cW2[t];
  int r8 = t >> 5, c = t & 31;
  int row = blockIdx.x*8 + r8;
  float e = enc2[(size_t)row*32 + c];
  e2[r8][c] = e;
  __syncthreads();
  float a = mb1[c];
  #pragma unroll
  for (int i = 0; i < 32; ++i) a += e2[r8][i]*s_mW1[i][c];
  t1[r8][c] = fmaxf(a, 0.f);
  __syncthreads();
  float o = e + mb2[c];
  #pragma unroll
  for (int i = 0; i < 32; ++i) o += t1[r8][i]*s_mW2[i][c];
  ov[r8][c] = o;
  __syncthreads();
  if (c < 16){
    float a2 = bb1[c];
    #pragma unroll
    for (int i = 0; i < 32; ++i) a2 += ov[r8][i]*s_bW1[i][c];
    bt[r8][c] = fmaxf(a2, 0.f);
  } else {
    int cc = c - 16;
    float a2 = cb1[cc];
    #pragma unroll
    for (int i = 0; i < 32; ++i) a2 += ov[r8][i]*s_cW1[i][cc];
    ct[r8][cc] = fmaxf(a2, 0.f);
  }
  __syncthreads();
  if (c == 0){
    float a3 = bb2[0];
    #pragma unroll
    for (int i = 0; i < 16; ++i) a3 += bt[r8][i]*s_bW2[i];
    float sg = 1.0f / (1.0f + __expf(-a3));
    sg = fminf(fmaxf(sg, 1e-6f), 1.0f - 1e-6f);
    outp[row] = sg;
  } else if (c < 4){
    int dd = c - 1;
    float a3 = cb2[dd];
    #pragma unroll
    for (int i = 0; i < 16; ++i) a3 += ct[r8][i]*s_cW2[i][dd];
    outp[(size_t)N + (size_t)row*3 + dd] = a3;
  }
}

// ====================================================================
extern "C" void kernel_launch(void* const* d_in, const int* in_sizes, int n_in,
                              void* d_out, int out_size, void* d_ws, size_t ws_size,
                              hipStream_t stream)
{
  const float* x       = (const float*)d_in[0];
  const float* coords  = (const float*)d_in[1];
  const int*   batch   = (const int*)d_in[2];
  const float* enc_W1  = (const float*)d_in[3];
  const float* enc_b1  = (const float*)d_in[4];
  const float* enc_W2  = (const float*)d_in[5];
  const float* enc_b2  = (const float*)d_in[6];
  const float* ln1_g   = (const float*)d_in[7];
  const float* ln1_b   = (const float*)d_in[8];
  const float* wq      = (const float*)d_in[9];
  const float* wk      = (const float*)d_in[10];
  const float* wv      = (const float*)d_in[11];
  const float* rpe_W   = (const float*)d_in[12];
  const float* wo      = (const float*)d_in[13];
  const float* ln2_g   = (const float*)d_in[14];
  const float* ln2_b   = (const float*)d_in[15];
  const float* ff_W1   = (const float*)d_in[16];
  const float* ff_b1   = (const float*)d_in[17];
  const float* ff_W2   = (const float*)d_in[18];
  const float* ff_b2   = (const float*)d_in[19];
  const float* W_cat   = (const float*)d_in[20];
  const float* mlp_W1  = (const float*)d_in[21];
  const float* mlp_b1  = (const float*)d_in[22];
  const float* mlp_W2  = (const float*)d_in[23];
  const float* mlp_b2  = (const float*)d_in[24];
  const float* beta_W1 = (const float*)d_in[25];
  const float* beta_b1 = (const float*)d_in[26];
  const float* beta_W2 = (const float*)d_in[27];
  const float* beta_b2 = (const float*)d_in[28];
  const float* coord_W1= (const float*)d_in[29];
  const float* coord_b1= (const float*)d_in[30];
  const float* coord_W2= (const float*)d_in[31];
  const float* coord_b2= (const float*)d_in[32];
  const float* hash_proj=(const float*)d_in[33];

  const int N  = in_sizes[0] / 16;
  const int nb = N / 128;
  float* outp = (float*)d_out;
  (void)out_size; (void)ws_size; (void)n_in;

  char* p = (char*)d_ws;
  size_t off = 0;
  auto alloc = [&](size_t bytes) -> char* {
    char* r = p + off;
    off += (bytes + 255) & ~(size_t)255;
    return r;
  };
  float* cur    = (float*)alloc((size_t)N*64*4);
  unsigned short* xnb = (unsigned short*)alloc((size_t)N*64*2);
  unsigned short* o_buf = (unsigned short*)alloc((size_t)3*N*512*2);
  float* enc2   = (float*)alloc((size_t)N*32*4);
  float* lse    = (float*)alloc((size_t)3*N*8*4);
  unsigned long long* keys = (unsigned long long*)alloc((size_t)3*N*8);
  int* idx      = (int*)alloc((size_t)3*N*4);
  unsigned short* wqkvT = (unsigned short*)alloc((size_t)4*3*512*64*2);
  unsigned short* woT   = (unsigned short*)alloc((size_t)4*64*512*2);
  unsigned* mm  = (unsigned*)alloc(256);
  float* whead  = (float*)alloc(256);

  // ---- weight convert/transpose + whead (all layers, once) ----
  wconv_kernel<<<2048, 256, 0, stream>>>(wq, wk, wv, wo, wqkvT, woT);
  whead_kernel<<<32, 64, 0, stream>>>(rpe_W, whead);

  // ---- sort keys (3 hash rounds, once) ----
  minmax_init_kernel<<<1, 64, 0, stream>>>(mm);
  minmax_reduce_kernel<<<64, 256, 0, stream>>>(coords, hash_proj, mm, N);
  make_keys_kernel<<<(N+255)/256, 256, 0, stream>>>(coords, batch, hash_proj, mm, keys, N);
  bitonic_local_full2k_kernel<<<dim3(N/2048, 3), 1024, 0, stream>>>(keys, N);
  for (int kk = 4096; kk <= N; kk <<= 1){
    for (int j = kk >> 1; j >= 2048; j >>= 1)
      bitonic_global_kernel<<<dim3(N/256, 3), 256, 0, stream>>>(keys, N, kk, j);
    bitonic_local_merge2k_kernel<<<dim3(N/2048, 3), 1024, 0, stream>>>(keys, N, kk);
  }
  extract_idx_kernel<<<(3*N+255)/256, 256, 0, stream>>>(keys, idx, 3*N);

  // ---- encoder (+ fused layer-0 LN) + feats[0] contribution to enc2 ----
  encoder_kernel<<<N/4, 256, 0, stream>>>(x, enc_W1, enc_b1, enc_W2, enc_b2,
      ln1_g, ln1_b, cur, xnb, N);
  enc2_accum_kernel<<<N/32, 256, 0, stream>>>(cur, W_cat, enc2, 0, 1, N);

  // ---- layers ----
  for (int l = 0; l < 4; ++l){
    attn_kernel<<<dim3(nb, 8, 3), 256, 0, stream>>>(xnb,
        wqkvT + (size_t)l*3*512*64, coords, batch, idx, whead + l*8, lse, o_buf, N);
    wo_mfma_kernel<<<N/64, 256, 0, stream>>>(o_buf, lse, woT + (size_t)l*64*512, cur, N);
    const float* nlg = (l < 3) ? (ln1_g + (l+1)*64) : nullptr;
    const float* nlb = (l < 3) ? (ln1_b + (l+1)*64) : nullptr;
    ffn_kernel<<<N/4, 256, 0, stream>>>(cur, ln2_g + l*64, ln2_b + l*64,
        ff_W1 + (size_t)l*64*64, ff_b1 + l*64, ff_W2 + (size_t)l*64*64, ff_b2 + l*64,
        nlg, nlb, xnb, N);
    enc2_accum_kernel<<<N/32, 256, 0, stream>>>(cur, W_cat, enc2, (l+1)*64, 0, N);
  }

  // ---- head ----
  head_kernel<<<N/8, 256, 0, stream>>>(enc2, mlp_W1, mlp_b1, mlp_W2, mlp_b2,
      beta_W1, beta_b1, beta_W2, beta_b2, coord_W1, coord_b1, coord_W2, coord_b2, outp, N);
}

// Round 9
// 726.955 us; speedup vs baseline: 1.1549x; 1.0835x over previous
//
#include <hip/hip_runtime.h>
#include <math.h>

#define DEV __device__ __forceinline__

constexpr int DHc = 64;
constexpr int HDc = 512;
constexpr int Hc  = 8;
constexpr int BLKc = 128;

typedef float f32x16 __attribute__((ext_vector_type(16)));
typedef short s16x8  __attribute__((ext_vector_type(8)));

union FragU { unsigned u[4]; s16x8 v; };

// ---------- float <-> order-preserving uint ----------
DEV unsigned fenc(float f){ unsigned u = __float_as_uint(f); return (u & 0x80000000u) ? ~u : (u | 0x80000000u); }
DEV float fdec(unsigned u){ unsigned b = (u & 0x80000000u) ? (u ^ 0x80000000u) : ~u; return __uint_as_float(b); }
DEV float hv_calc(float c0, float c1, float h0, float h1){
  return __fadd_rn(__fmul_rn(c0, h0), __fmul_rn(c1, h1));
}
// bf16 encode (round-to-nearest-even) / decode
DEV unsigned short f2bf(float f){
  unsigned u = __float_as_uint(f);
  return (unsigned short)((u + 0x7FFFu + ((u >> 16) & 1u)) >> 16);
}
DEV float bf2f(unsigned short s){ return __uint_as_float((unsigned)s << 16); }

// pack two f32 -> bf16x2 via HW cvt_pk — NOT RNE (biased); ONLY safe for P (empirically verified)
DEV unsigned cvtpk(float lo, float hi){
  unsigned r;
  asm("v_cvt_pk_bf16_f32 %0, %1, %2" : "=v"(r) : "v"(lo), "v"(hi));
  return r;
}
// explicit-RNE pack — required for persistent tensors (V etc.)
DEV unsigned pack_bf2(float lo, float hi){
  return (unsigned)f2bf(lo) | ((unsigned)f2bf(hi) << 16);
}
// v_permlane32_swap_b32
DEV void pswap(unsigned &a, unsigned &b){
  asm volatile("v_permlane32_swap_b32 %0, %1" : "+v"(a), "+v"(b));
}

// ---------- min/max reductions for sort keys ----------
__global__ void minmax_init_kernel(unsigned* mm){
  int t = threadIdx.x;
  if (t < 4) mm[t] = 0xFFFFFFFFu;
  else if (t < 8) mm[t] = 0u;
}

__global__ __launch_bounds__(256) void minmax_reduce_kernel(const float* __restrict__ coords,
    const float* __restrict__ hp, unsigned* mm, int N)
{
  __shared__ float red[4][8];
  float h[6];
  #pragma unroll
  for (int i = 0; i < 6; ++i) h[i] = hp[i];
  float mn[4] = {3.0e38f, 3.0e38f, 3.0e38f, 3.0e38f};
  float mx[4] = {-3.0e38f, -3.0e38f, -3.0e38f, -3.0e38f};
  for (int i = blockIdx.x*blockDim.x + threadIdx.x; i < N; i += gridDim.x*blockDim.x){
    float2 c = *(const float2*)&coords[2*i];
    float v0 = c.x;
    float v1 = hv_calc(c.x, c.y, h[0], h[1]);
    float v2 = hv_calc(c.x, c.y, h[2], h[3]);
    float v3 = hv_calc(c.x, c.y, h[4], h[5]);
    mn[0] = fminf(mn[0], v0); mx[0] = fmaxf(mx[0], v0);
    mn[1] = fminf(mn[1], v1); mx[1] = fmaxf(mx[1], v1);
    mn[2] = fminf(mn[2], v2); mx[2] = fmaxf(mx[2], v2);
    mn[3] = fminf(mn[3], v3); mx[3] = fmaxf(mx[3], v3);
  }
  #pragma unroll
  for (int o = 1; o < 64; o <<= 1){
    #pragma unroll
    for (int s = 0; s < 4; ++s){
      mn[s] = fminf(mn[s], __shfl_xor(mn[s], o));
      mx[s] = fmaxf(mx[s], __shfl_xor(mx[s], o));
    }
  }
  int w = threadIdx.x >> 6;
  if ((threadIdx.x & 63) == 0){
    #pragma unroll
    for (int s = 0; s < 4; ++s){ red[w][s] = mn[s]; red[w][4+s] = mx[s]; }
  }
  __syncthreads();
  int t = threadIdx.x;
  if (t < 4){
    float v = fminf(fminf(red[0][t], red[1][t]), fminf(red[2][t], red[3][t]));
    atomicMin(&mm[t], fenc(v));
  } else if (t < 8){
    float v = fmaxf(fmaxf(red[0][t], red[1][t]), fmaxf(red[2][t], red[3][t]));
    atomicMax(&mm[t], fenc(v));
  }
}

__global__ void make_keys_kernel(const float* __restrict__ coords, const int* __restrict__ batch,
                                 const float* __restrict__ hp, const unsigned* __restrict__ mm,
                                 unsigned long long* __restrict__ keys, int N)
{
  int i = blockIdx.x*blockDim.x + threadIdx.x;
  if (i >= N) return;
  float c0 = coords[2*i], c1 = coords[2*i+1];
  float c0min = fdec(mm[0]), c0max = fdec(mm[4]);
  float rf = (c0 - c0min) / (c0max - c0min + 1e-6f) * 8.0f;
  int region = (int)rf;
  region = region < 0 ? 0 : (region > 7 ? 7 : region);
  float base2 = ((float)batch[i] * 8.0f + (float)region) * 2.0f;
  #pragma unroll
  for (int r = 0; r < 3; ++r){
    float hv = hv_calc(c0, c1, hp[2*r], hp[2*r+1]);
    float hn = (hv - fdec(mm[1+r])) / (fdec(mm[5+r]) - fdec(mm[1+r]) + 1e-6f);
    float skey = base2 + hn;
    keys[(size_t)r*N + i] = ((unsigned long long)__float_as_uint(skey) << 32) | (unsigned)i;
  }
}

// ---------- bitonic sort, 2048-element local tiles (thread-per-pair) ----------
__global__ __launch_bounds__(1024) void bitonic_local_full2k_kernel(unsigned long long* keys, int N)
{
  __shared__ unsigned long long sh[2048];
  unsigned long long* a = keys + (size_t)blockIdx.y * N;
  int base = blockIdx.x * 2048, t = threadIdx.x;
  sh[t] = a[base + t];
  sh[t + 1024] = a[base + t + 1024];
  __syncthreads();
  for (int k = 2; k <= 2048; k <<= 1){
    for (int j = k >> 1; j > 0; j >>= 1){
      int i = ((t & ~(j-1)) << 1) | (t & (j-1));
      bool dirup = (((base + i) & k) == 0);
      unsigned long long x = sh[i], y = sh[i+j];
      if ((x > y) == dirup){ sh[i] = y; sh[i+j] = x; }
      __syncthreads();
    }
  }
  a[base + t] = sh[t];
  a[base + t + 1024] = sh[t + 1024];
}

__global__ void bitonic_global_kernel(unsigned long long* keys, int N, int k, int j)
{
  unsigned long long* a = keys + (size_t)blockIdx.y * N;
  int i = blockIdx.x*blockDim.x + threadIdx.x;
  int l = i ^ j;
  if (l > i && l < N){
    unsigned long long x = a[i], y = a[l];
    bool dirup = ((i & k) == 0);
    if ((x > y) == dirup){ a[i] = y; a[l] = x; }
  }
}

__global__ __launch_bounds__(1024) void bitonic_local_merge2k_kernel(unsigned long long* keys, int N, int k)
{
  __shared__ unsigned long long sh[2048];
  unsigned long long* a = keys + (size_t)blockIdx.y * N;
  int base = blockIdx.x * 2048, t = threadIdx.x;
  sh[t] = a[base + t];
  sh[t + 1024] = a[base + t + 1024];
  __syncthreads();
  for (int j = 1024; j > 0; j >>= 1){
    int i = ((t & ~(j-1)) << 1) | (t & (j-1));
    bool dirup = (((base + i) & k) == 0);
    unsigned long long x = sh[i], y = sh[i+j];
    if ((x > y) == dirup){ sh[i] = y; sh[i+j] = x; }
    __syncthreads();
  }
  a[base + t] = sh[t];
  a[base + t + 1024] = sh[t + 1024];
}

__global__ void extract_idx_kernel(const unsigned long long* __restrict__ keys, int* __restrict__ idx, int total)
{
  int i = blockIdx.x*blockDim.x + threadIdx.x;
  if (i < total) idx[i] = (int)(keys[i] & 0xFFFFFFFFull);
}

// ---------- weight convert+transpose (once): wqkvT[l][z][n][k], woT[l][n][k] ----------
__global__ void wconv_kernel(const float* __restrict__ wq, const float* __restrict__ wk,
                             const float* __restrict__ wv, const float* __restrict__ wo,
                             unsigned short* __restrict__ wqkvT, unsigned short* __restrict__ woT)
{
  int tid = blockIdx.x*blockDim.x + threadIdx.x;
  const int NQ = 4*3*512*64;
  if (tid < NQ){
    int kk = tid & 63;
    int rest = tid >> 6;
    int n = rest & 511;
    int rest2 = rest >> 9;
    int z = rest2 % 3, l = rest2 / 3;
    const float* W = (z==0) ? wq : (z==1) ? wk : wv;
    wqkvT[tid] = f2bf(W[((size_t)l*64 + kk)*512 + n]);
  } else if (tid < NQ + 4*64*512){
    int e = tid - NQ;
    int kk = e & 511;
    int rest = e >> 9;
    int n = rest & 63;
    int l = rest >> 6;
    woT[e] = f2bf(wo[((size_t)l*512 + kk)*64 + n]);
  }
}

// ---------- M = 0.125 * Wq_h Wk_h^T per (layer,head), stored transposed Mt[j][i] (bf16) ----------
__global__ __launch_bounds__(256) void mqk_kernel(const float* __restrict__ wq,
    const float* __restrict__ wk, unsigned short* __restrict__ mqk)
{
  __shared__ float qs[64][64];
  __shared__ float ks_[64][64];
  int blk = blockIdx.x;          // l*8 + h
  int l = blk >> 3, h = blk & 7;
  int t = threadIdx.x;
  for (int f = t; f < 4096; f += 256){
    int i = f >> 6, d = f & 63;
    qs[i][d]  = wq[((size_t)l*64 + i)*512 + h*64 + d];
    ks_[i][d] = wk[((size_t)l*64 + i)*512 + h*64 + d];
  }
  __syncthreads();
  int j = t >> 2, i0 = (t & 3) * 16;
  unsigned short* outp = mqk + (size_t)blk*4096 + j*64;
  #pragma unroll
  for (int ii = 0; ii < 16; ++ii){
    int i = i0 + ii;
    float acc = 0.f;
    #pragma unroll
    for (int d = 0; d < 64; ++d) acc += qs[i][d]*ks_[j][d];
    outp[i] = f2bf(acc * 0.125f);
  }
}

// ---------- encoder: h0 = relu(x@W1+b1)@W2+b2; fused LN(layer0) -> xnb ----------
__global__ __launch_bounds__(256) void encoder_kernel(const float* __restrict__ x,
    const float* __restrict__ W1, const float* __restrict__ b1,
    const float* __restrict__ W2, const float* __restrict__ b2,
    const float* __restrict__ lng, const float* __restrict__ lnb,
    float* __restrict__ h0, unsigned short* __restrict__ xnb, int N)
{
  __shared__ float W1s[16][64];
  __shared__ __align__(16) float W2s[64][64];
  __shared__ float xs[4][16];
  __shared__ float t1s[4][64];
  int t = threadIdx.x;
  for (int f = t; f < 1024; f += 256) W1s[f>>6][f&63] = W1[f];
  #pragma unroll
  for (int e = 0; e < 4; ++e){ int f = t + e*256; *(float4*)&W2s[f>>4][(f&15)*4] = *(const float4*)&W2[f*4]; }
  int w = t >> 6, d = t & 63;
  int row = blockIdx.x*4 + w;
  if (d < 16) xs[w][d] = x[(size_t)row*16 + d];
  __syncthreads();
  float acc = b1[d];
  #pragma unroll
  for (int i = 0; i < 16; ++i) acc += xs[w][i]*W1s[i][d];
  t1s[w][d] = fmaxf(acc, 0.f);
  __syncthreads();
  float acc2 = b2[d];
  #pragma unroll
  for (int i = 0; i < 64; ++i) acc2 += t1s[w][i]*W2s[i][d];
  h0[(size_t)row*64 + d] = acc2;
  // fused LN for layer 0
  float s = acc2;
  #pragma unroll
  for (int o = 1; o < 64; o <<= 1) s += __shfl_xor(s, o);
  float mean = s * (1.0f/64.0f);
  float dv = acc2 - mean, sq = dv*dv;
  #pragma unroll
  for (int o = 1; o < 64; o <<= 1) sq += __shfl_xor(sq, o);
  xnb[(size_t)row*64 + d] = f2bf(dv * rsqrtf(sq*(1.0f/64.0f) + 1e-5f) * lng[d] + lnb[d]);
}

// ---------- w_head (all 4 layers, once) ----------
__global__ void whead_kernel(const float* __restrict__ rpe, float* __restrict__ wh)
{
  int l = blockIdx.x >> 3, h = blockIdx.x & 7, d = threadIdx.x;
  const float* rp = rpe + (size_t)l*8*512;
  float s = 0.f;
  #pragma unroll
  for (int w = 0; w < 8; ++w) s += rp[(size_t)w*512 + h*64 + d];
  #pragma unroll
  for (int o = 1; o < 64; o <<= 1) s += __shfl_xor(s, o);
  if (d == 0){
    float m = s * (1.0f/512.0f);
    wh[blockIdx.x] = fmaxf(m, 0.f) + log1pf(expf(-fabsf(m)));
  }
}

// ============ fused attention: S = X M X^T (M-trick), T/V MFMA, single-pass softmax ============
__global__ __launch_bounds__(256, 3) void attn_kernel(
    const unsigned short* __restrict__ xnb, const unsigned short* __restrict__ wqkvT_l,
    const unsigned short* __restrict__ mqk_l,
    const float* __restrict__ coords, const int* __restrict__ batch,
    const int* __restrict__ idx_all, const float* __restrict__ w_head,
    float* __restrict__ lse_all, unsigned short* __restrict__ o_buf, int N)
{
  __shared__ __align__(16) unsigned short xlds[128*64];   // gathered X rows (A-operand for T/V/S)
  __shared__ __align__(16) unsigned short tlds[128*64];   // T = X @ M  (B-operand for S)
  __shared__ __align__(16) unsigned short vtl[64*128];    // V^T [d][k]
  __shared__ __align__(16) float c1s[BLKc];
  __shared__ __align__(16) int   bts[BLKc];
  __shared__ int   idxs[BLKc];
  __shared__ __align__(16) float isel[BLKc];
  __shared__ int unif;
  int b = blockIdx.x, h = blockIdx.y, r = blockIdx.z, t = threadIdx.x;
  const int* idx_r = idx_all + (size_t)r*N;
  if (t < BLKc){
    int g = idx_r[b*BLKc + t];
    idxs[t] = g; c1s[t] = coords[2*g+1]; bts[t] = batch[g];
  }
  __syncthreads();
  if (t == 0) unif = (bts[0] == bts[127]);
  // ---- stage gathered X rows -> xlds (swizzled row-major, verified round-5 pattern) ----
  #pragma unroll
  for (int e = 0; e < 4; ++e){
    int f = t + e*256;
    int row = f >> 3, ch = f & 7;
    int g = idxs[row];
    s16x8 xv = *(const s16x8*)&xnb[(size_t)g*64 + ch*8];
    *(s16x8*)&xlds[row*64 + ((ch ^ (row&7))*8)] = xv;
  }
  __syncthreads();

  int w = t >> 6, l = t & 63, lo = l & 31, hi = l >> 5;
  int arow = w*32 + lo;

  // A-frags: this wave's 32 X rows
  s16x8 af[4];
  #pragma unroll
  for (int ks = 0; ks < 4; ++ks)
    af[ks] = *(const s16x8*)&xlds[arow*64 + ((((ks<<1)|hi) ^ (arow&7))*8)];

  // ---- T = X @ M  (M streamed from global, 8 KB/head, L2-resident) ----
  {
    const unsigned short* Mt = mqk_l + (size_t)h*4096;
    f32x16 a0, a1;
    #pragma unroll
    for (int i = 0; i < 16; ++i){ a0[i] = 0.f; a1[i] = 0.f; }
    #pragma unroll
    for (int ks = 0; ks < 4; ++ks){
      s16x8 b0 = *(const s16x8*)&Mt[(size_t)(lo)*64      + ks*16 + hi*8];
      s16x8 b1 = *(const s16x8*)&Mt[(size_t)(32 + lo)*64 + ks*16 + hi*8];
      a0 = __builtin_amdgcn_mfma_f32_32x32x16_bf16(af[ks], b0, a0, 0, 0, 0);
      a1 = __builtin_amdgcn_mfma_f32_32x32x16_bf16(af[ks], b1, a1, 0, 0, 0);
    }
    int ch0 = lo >> 3, ch1 = 4 + (lo >> 3), co = lo & 7;
    #pragma unroll
    for (int reg = 0; reg < 16; ++reg){
      int row = w*32 + (reg&3) + 8*(reg>>2) + 4*hi;
      tlds[row*64 + ((ch0 ^ (row&7))*8) + co] = f2bf(a0[reg]);
      tlds[row*64 + ((ch1 ^ (row&7))*8) + co] = f2bf(a1[reg]);
    }
  }
  // ---- V = X @ Wv  -> vtl [d][k] (explicit-RNE pack) ----
  {
    const unsigned short* wz = wqkvT_l + (size_t)2*512*64 + (size_t)h*64*64;
    f32x16 a0, a1;
    #pragma unroll
    for (int i = 0; i < 16; ++i){ a0[i] = 0.f; a1[i] = 0.f; }
    #pragma unroll
    for (int ks = 0; ks < 4; ++ks){
      s16x8 b0 = *(const s16x8*)&wz[(size_t)(lo)*64      + ks*16 + hi*8];
      s16x8 b1 = *(const s16x8*)&wz[(size_t)(32 + lo)*64 + ks*16 + hi*8];
      a0 = __builtin_amdgcn_mfma_f32_32x32x16_bf16(af[ks], b0, a0, 0, 0, 0);
      a1 = __builtin_amdgcn_mfma_f32_32x32x16_bf16(af[ks], b1, a1, 0, 0, 0);
    }
    #pragma unroll
    for (int rq = 0; rq < 4; ++rq){
      int k0 = w*32 + rq*8 + 4*hi;
      int cj = k0 >> 3;
      int d0 = lo, d1 = 32 + lo;
      unsigned* dp0 = (unsigned*)&vtl[d0*128 + ((cj ^ (d0&7))*8) + 4*hi];
      dp0[0] = pack_bf2(a0[rq*4+0], a0[rq*4+1]);
      dp0[1] = pack_bf2(a0[rq*4+2], a0[rq*4+3]);
      unsigned* dp1 = (unsigned*)&vtl[d1*128 + ((cj ^ (d1&7))*8) + 4*hi];
      dp1[0] = pack_bf2(a1[rq*4+0], a1[rq*4+1]);
      dp1[1] = pack_bf2(a1[rq*4+2], a1[rq*4+3]);
    }
  }
  __syncthreads();

  int qrow = arow;
  s16x8 tf[4];
  #pragma unroll
  for (int ks = 0; ks < 4; ++ks)
    tf[ks] = *(const s16x8*)&tlds[qrow*64 + ((((ks<<1)|hi) ^ (qrow&7))*8)];

  f32x16 acc[4];
  #pragma unroll
  for (int kt = 0; kt < 4; ++kt)
    #pragma unroll
    for (int i = 0; i < 16; ++i) acc[kt][i] = 0.f;

  __builtin_amdgcn_s_setprio(1);
  #pragma unroll
  for (int kt = 0; kt < 4; ++kt){
    int krow = kt*32 + lo;
    #pragma unroll
    for (int ks = 0; ks < 4; ++ks){
      s16x8 xf = *(const s16x8*)&xlds[krow*64 + ((((ks<<1)|hi) ^ (krow&7))*8)];
      acc[kt] = __builtin_amdgcn_mfma_f32_32x32x16_bf16(xf, tf[ks], acc[kt], 0, 0, 0);
    }
  }
  __builtin_amdgcn_s_setprio(0);

  float c1i = c1s[qrow]; int bti = bts[qrow];
  float wh = w_head[h];
  // scores + exp in one pass (no max-sub: |s| bounded << 88; masked -> exp(-1e9)=0)
  float se = 0.f;
#define SCORE_LOOP(MASKED)                                                   \
  _Pragma("unroll")                                                          \
  for (int kt = 0; kt < 4; ++kt){                                            \
    _Pragma("unroll")                                                        \
    for (int rq = 0; rq < 4; ++rq){                                          \
      int kb = kt*32 + rq*8 + hi*4;                                          \
      float4 c4 = *(const float4*)&c1s[kb];                                  \
      int4  b4 = *(const int4*)&bts[kb];                                     \
      _Pragma("unroll")                                                      \
      for (int j = 0; j < 4; ++j){                                           \
        int reg = rq*4 + j;                                                  \
        float c1k = (j==0)?c4.x:(j==1)?c4.y:(j==2)?c4.z:c4.w;                \
        int   btk = (j==0)?b4.x:(j==1)?b4.y:(j==2)?b4.z:b4.w;                \
        float dd = c1i - c1k;                                                \
        float sc = acc[kt][reg] - wh*dd*dd;                                  \
        if (MASKED && bti != btk) sc = -1e9f;                                \
        float pv = __expf(sc);                                               \
        acc[kt][reg] = pv;                                                   \
        se += pv;                                                            \
      }                                                                      \
    }                                                                        \
  }
  if (unif){ SCORE_LOOP(false) } else { SCORE_LOOP(true) }
#undef SCORE_LOOP
  se += __shfl_xor(se, 32);
  if (l < 32){
    int gi0 = idxs[qrow];
    lse_all[((size_t)r*N + gi0)*Hc + h] = __logf(se);
    isel[qrow] = 1.0f / se;
  }

  // PV via in-register bf16 pack (cvt_pk + permlane32_swap; cvt_pk OK for P only)
  f32x16 oa0, oa1;
  #pragma unroll
  for (int i = 0; i < 16; ++i){ oa0[i] = 0.f; oa1[i] = 0.f; }

  __builtin_amdgcn_s_setprio(1);
  #pragma unroll
  for (int kt = 0; kt < 4; ++kt){
    unsigned X = cvtpk(acc[kt][0],  acc[kt][1]);
    unsigned Z = cvtpk(acc[kt][2],  acc[kt][3]);
    unsigned Y = cvtpk(acc[kt][4],  acc[kt][5]);
    unsigned W = cvtpk(acc[kt][6],  acc[kt][7]);
    pswap(X, Y); pswap(Z, W);
    FragU f0; f0.u[0]=X; f0.u[1]=Z; f0.u[2]=Y; f0.u[3]=W;
    unsigned X2 = cvtpk(acc[kt][8],  acc[kt][9]);
    unsigned Z2 = cvtpk(acc[kt][10], acc[kt][11]);
    unsigned Y2 = cvtpk(acc[kt][12], acc[kt][13]);
    unsigned W2 = cvtpk(acc[kt][14], acc[kt][15]);
    pswap(X2, Y2); pswap(Z2, W2);
    FragU f1; f1.u[0]=X2; f1.u[1]=Z2; f1.u[2]=Y2; f1.u[3]=W2;
    #pragma unroll
    for (int hks = 0; hks < 2; ++hks){
      s16x8 pa = hks ? f1.v : f0.v;
      int kch = kt*4 + hks*2 + hi;
      int d0 = lo;
      s16x8 vf0 = *(const s16x8*)&vtl[d0*128 + ((kch ^ (d0&7))*8)];
      oa0 = __builtin_amdgcn_mfma_f32_32x32x16_bf16(pa, vf0, oa0, 0, 0, 0);
      int d1 = 32 + lo;
      s16x8 vf1 = *(const s16x8*)&vtl[d1*128 + ((kch ^ (d1&7))*8)];
      oa1 = __builtin_amdgcn_mfma_f32_32x32x16_bf16(pa, vf1, oa1, 0, 0, 0);
    }
  }
  __builtin_amdgcn_s_setprio(0);

  // epilogue: o_r[g][h*64 + d] = bf16(O / se)
  unsigned short* orow = o_buf + (size_t)r*N*HDc;
  #pragma unroll
  for (int rq = 0; rq < 4; ++rq){
    float4 s4 = *(const float4*)&isel[w*32 + rq*8 + hi*4];
    #pragma unroll
    for (int j = 0; j < 4; ++j){
      int reg = rq*4 + j;
      int qq = rq*8 + hi*4 + j;
      int g = idxs[w*32 + qq];
      float sv = (j==0)?s4.x:(j==1)?s4.y:(j==2)?s4.z:s4.w;
      unsigned short* dst = &orow[(size_t)g*HDc + h*DHc + lo];
      dst[0]  = f2bf(oa0[reg]*sv);
      dst[32] = f2bf(oa1[reg]*sv);
    }
  }
  (void)b;
}

// ---------- WO MFMA with fused cross-round combine ----------
__global__ __launch_bounds__(256) void wo_mfma_kernel(
    const unsigned short* __restrict__ o_buf, const float* __restrict__ lse_all,
    const unsigned short* __restrict__ woT_l, float* __restrict__ cur, int N)
{
  __shared__ __align__(16) unsigned short As[64*128];
  __shared__ __align__(16) unsigned short Bs[64*128];
  __shared__ float wts[64][24];
  int rb = blockIdx.x*64, t = threadIdx.x;
  #pragma unroll
  for (int e = 0; e < 2; ++e){
    int p = t + e*256;
    int rr = p >> 3, h = p & 7;
    float l0 = lse_all[((size_t)0*N + rb+rr)*Hc + h];
    float l1 = lse_all[((size_t)1*N + rb+rr)*Hc + h];
    float l2 = lse_all[((size_t)2*N + rb+rr)*Hc + h];
    float lm = fmaxf(l0, fmaxf(l1, l2));
    float e0 = __expf(l0-lm), e1 = __expf(l1-lm), e2 = __expf(l2-lm);
    float inv = 1.0f/(e0+e1+e2);
    wts[rr][h*3+0] = e0*inv; wts[rr][h*3+1] = e1*inv; wts[rr][h*3+2] = e2*inv;
  }
  int w = t >> 6, l = t & 63, lo = l & 31, hi = l >> 5;
  int mt = w >> 1, nt = w & 1;
  f32x16 acc;
  #pragma unroll
  for (int i = 0; i < 16; ++i) acc[i] = 0.f;
  for (int kt = 0; kt < 4; ++kt){
    __syncthreads();
    #pragma unroll
    for (int e = 0; e < 4; ++e){
      int f = t + e*256; int rr = f >> 4, kc = f & 15;
      int k0 = kt*128 + kc*8;
      int h = k0 >> 6;
      float w0 = wts[rr][h*3+0], w1 = wts[rr][h*3+1], w2 = wts[rr][h*3+2];
      s16x8 u0 = *(const s16x8*)&o_buf[((size_t)0*N + rb+rr)*HDc + k0];
      s16x8 u1 = *(const s16x8*)&o_buf[((size_t)1*N + rb+rr)*HDc + k0];
      s16x8 u2 = *(const s16x8*)&o_buf[((size_t)2*N + rb+rr)*HDc + k0];
      FragU fo;
      #pragma unroll
      for (int ii = 0; ii < 4; ++ii){
        float a0 = w0*bf2f((unsigned short)u0[2*ii])   + w1*bf2f((unsigned short)u1[2*ii])   + w2*bf2f((unsigned short)u2[2*ii]);
        float a1 = w0*bf2f((unsigned short)u0[2*ii+1]) + w1*bf2f((unsigned short)u1[2*ii+1]) + w2*bf2f((unsigned short)u2[2*ii+1]);
        fo.u[ii] = cvtpk(a0, a1);
      }
      *(s16x8*)&As[rr*128 + ((kc ^ (rr&7))*8)] = fo.v;
      *(s16x8*)&Bs[rr*128 + ((kc ^ (rr&7))*8)] = *(const s16x8*)&woT_l[(size_t)rr*512 + k0];
    }
    __syncthreads();
    #pragma unroll
    for (int ks = 0; ks < 8; ++ks){
      int s = ks*2 + hi;
      int arow = mt*32 + lo, brow = nt*32 + lo;
      s16x8 af = *(const s16x8*)&As[arow*128 + ((s ^ (arow&7))*8)];
      s16x8 bfr = *(const s16x8*)&Bs[brow*128 + ((s ^ (brow&7))*8)];
      acc = __builtin_amdgcn_mfma_f32_32x32x16_bf16(af, bfr, acc, 0, 0, 0);
    }
  }
  #pragma unroll
  for (int reg = 0; reg < 16; ++reg){
    int m = mt*32 + (reg&3) + 8*(reg>>2) + 4*hi;
    int n = nt*32 + lo;
    cur[(size_t)(rb+m)*64 + n] += acc[reg];
  }
}

// ---------- FFN: cur += relu(LN(cur)@W1+b1)@W2+b2; fused next-layer LN -> xnb ----------
__global__ __launch_bounds__(256) void ffn_kernel(float* __restrict__ cur,
    const float* __restrict__ g, const float* __restrict__ bln,
    const float* __restrict__ W1, const float* __restrict__ b1,
    const float* __restrict__ W2, const float* __restrict__ b2,
    const float* __restrict__ nlg, const float* __restrict__ nlb,
    unsigned short* __restrict__ xnb, int N)
{
  __shared__ __align__(16) float W1s[64][64];
  __shared__ __align__(16) float W2s[64][64];
  __shared__ float xns[4][64];
  __shared__ float t1s[4][64];
  int t = threadIdx.x;
  #pragma unroll
  for (int e = 0; e < 4; ++e){
    int f = t + e*256; int rr = f >> 4, c4 = f & 15;
    *(float4*)&W1s[rr][c4*4] = *(const float4*)&W1[f*4];
    *(float4*)&W2s[rr][c4*4] = *(const float4*)&W2[f*4];
  }
  int w = t >> 6, d = t & 63;
  int row = blockIdx.x*4 + w;
  float v = cur[(size_t)row*64 + d];
  float s = v;
  #pragma unroll
  for (int o = 1; o < 64; o <<= 1) s += __shfl_xor(s, o);
  float mean = s * (1.0f/64.0f);
  float dv = v - mean, sq = dv*dv;
  #pragma unroll
  for (int o = 1; o < 64; o <<= 1) sq += __shfl_xor(sq, o);
  float xnv = dv * rsqrtf(sq*(1.0f/64.0f) + 1e-5f) * g[d] + bln[d];
  xns[w][d] = xnv;
  __syncthreads();
  float acc = b1[d];
  #pragma unroll
  for (int i = 0; i < 64; ++i) acc += xns[w][i]*W1s[i][d];
  t1s[w][d] = fmaxf(acc, 0.f);
  __syncthreads();
  float acc2 = b2[d];
  #pragma unroll
  for (int i = 0; i < 64; ++i) acc2 += t1s[w][i]*W2s[i][d];
  float nv = v + acc2;
  cur[(size_t)row*64 + d] = nv;
  if (nlg){
    float s2 = nv;
    #pragma unroll
    for (int o = 1; o < 64; o <<= 1) s2 += __shfl_xor(s2, o);
    float mean2 = s2 * (1.0f/64.0f);
    float dv2 = nv - mean2, sq2 = dv2*dv2;
    #pragma unroll
    for (int o = 1; o < 64; o <<= 1) sq2 += __shfl_xor(sq2, o);
    xnb[(size_t)row*64 + d] = f2bf(dv2 * rsqrtf(sq2*(1.0f/64.0f) + 1e-5f) * nlg[d] + nlb[d]);
  }
}

// ---------- enc2 (+)= cur @ W_cat[rowoff:rowoff+64, :]  (32 rows/block) ----------
__global__ __launch_bounds__(256) void enc2_accum_kernel(const float* __restrict__ cur,
    const float* __restrict__ Wcat, float* __restrict__ enc2, int rowoff, int store, int N)
{
  __shared__ float Ws[64][33];
  __shared__ float crs[32][65];
  int t = threadIdx.x;
  for (int f = t; f < 2048; f += 256) Ws[f>>5][f&31] = Wcat[(size_t)(rowoff + (f>>5))*32 + (f&31)];
  for (int f = t; f < 2048; f += 256) crs[f>>6][f&63] = cur[(size_t)(blockIdx.x*32 + (f>>6))*64 + (f&63)];
  __syncthreads();
  int r8 = t >> 5, c = t & 31;
  for (int rr = r8; rr < 32; rr += 8){
    int row = blockIdx.x*32 + rr;
    float acc = 0.f;
    #pragma unroll
    for (int d = 0; d < 64; ++d) acc += crs[rr][d]*Ws[d][c];
    size_t o = (size_t)row*32 + c;
    if (store) enc2[o] = acc; else enc2[o] += acc;
  }
}

// ---------- final head ----------
__global__ __launch_bounds__(256) void head_kernel(const float* __restrict__ enc2,
    const float* mW1, const float* mb1, const float* mW2, const float* mb2,
    const float* bW1, const float* bb1, const float* bW2, const float* bb2,
    const float* cW1, const float* cb1, const float* cW2, const float* cb2,
    float* __restrict__ outp, int N)
{
  __shared__ float s_mW1[32][32], s_mW2[32][32], s_bW1[32][16], s_cW1[32][16];
  __shared__ float s_bW2[16], s_cW2[16][3];
  __shared__ float e2[8][32], t1[8][32], ov[8][32], bt[8][16], ct[8][16];
  int t = threadIdx.x;
  for (int f = t; f < 1024; f += 256){ s_mW1[f>>5][f&31] = mW1[f]; s_mW2[f>>5][f&31] = mW2[f]; }
  for (int f = t; f < 512; f += 256){ s_bW1[f>>4][f&15] = bW1[f]; s_cW1[f>>4][f&15] = cW1[f]; }
  if (t < 16) s_bW2[t] = bW2[t];
  if (t < 48) s_cW2[t/3][t%3] = cW2[t];
  int r8 = t >> 5, c = t & 31;
  int row = blockIdx.x*8 + r8;
  float e = enc2[(size_t)row*32 + c];
  e2[r8][c] = e;
  __syncthreads();
  float a = mb1[c];
  #pragma unroll
  for (int i = 0; i < 32; ++i) a += e2[r8][i]*s_mW1[i][c];
  t1[r8][c] = fmaxf(a, 0.f);
  __syncthreads();
  float o = e + mb2[c];
  #pragma unroll
  for (int i = 0; i < 32; ++i) o += t1[r8][i]*s_mW2[i][c];
  ov[r8][c] = o;
  __syncthreads();
  if (c < 16){
    float a2 = bb1[c];
    #pragma unroll
    for (int i = 0; i < 32; ++i) a2 += ov[r8][i]*s_bW1[i][c];
    bt[r8][c] = fmaxf(a2, 0.f);
  } else {
    int cc = c - 16;
    float a2 = cb1[cc];
    #pragma unroll
    for (int i = 0; i < 32; ++i) a2 += ov[r8][i]*s_cW1[i][cc];
    ct[r8][cc] = fmaxf(a2, 0.f);
  }
  __syncthreads();
  if (c == 0){
    float a3 = bb2[0];
    #pragma unroll
    for (int i = 0; i < 16; ++i) a3 += bt[r8][i]*s_bW2[i];
    float sg = 1.0f / (1.0f + __expf(-a3));
    sg = fminf(fmaxf(sg, 1e-6f), 1.0f - 1e-6f);
    outp[row] = sg;
  } else if (c < 4){
    int dd = c - 1;
    float a3 = cb2[dd];
    #pragma unroll
    for (int i = 0; i < 16; ++i) a3 += ct[r8][i]*s_cW2[i][dd];
    outp[(size_t)N + (size_t)row*3 + dd] = a3;
  }
}

// ====================================================================
extern "C" void kernel_launch(void* const* d_in, const int* in_sizes, int n_in,
                              void* d_out, int out_size, void* d_ws, size_t ws_size,
                              hipStream_t stream)
{
  const float* x       = (const float*)d_in[0];
  const float* coords  = (const float*)d_in[1];
  const int*   batch   = (const int*)d_in[2];
  const float* enc_W1  = (const float*)d_in[3];
  const float* enc_b1  = (const float*)d_in[4];
  const float* enc_W2  = (const float*)d_in[5];
  const float* enc_b2  = (const float*)d_in[6];
  const float* ln1_g   = (const float*)d_in[7];
  const float* ln1_b   = (const float*)d_in[8];
  const float* wq      = (const float*)d_in[9];
  const float* wk      = (const float*)d_in[10];
  const float* wv      = (const float*)d_in[11];
  const float* rpe_W   = (const float*)d_in[12];
  const float* wo      = (const float*)d_in[13];
  const float* ln2_g   = (const float*)d_in[14];
  const float* ln2_b   = (const float*)d_in[15];
  const float* ff_W1   = (const float*)d_in[16];
  const float* ff_b1   = (const float*)d_in[17];
  const float* ff_W2   = (const float*)d_in[18];
  const float* ff_b2   = (const float*)d_in[19];
  const float* W_cat   = (const float*)d_in[20];
  const float* mlp_W1  = (const float*)d_in[21];
  const float* mlp_b1  = (const float*)d_in[22];
  const float* mlp_W2  = (const float*)d_in[23];
  const float* mlp_b2  = (const float*)d_in[24];
  const float* beta_W1 = (const float*)d_in[25];
  const float* beta_b1 = (const float*)d_in[26];
  const float* beta_W2 = (const float*)d_in[27];
  const float* beta_b2 = (const float*)d_in[28];
  const float* coord_W1= (const float*)d_in[29];
  const float* coord_b1= (const float*)d_in[30];
  const float* coord_W2= (const float*)d_in[31];
  const float* coord_b2= (const float*)d_in[32];
  const float* hash_proj=(const float*)d_in[33];

  const int N  = in_sizes[0] / 16;
  const int nb = N / 128;
  float* outp = (float*)d_out;
  (void)out_size; (void)ws_size; (void)n_in;

  char* p = (char*)d_ws;
  size_t off = 0;
  auto alloc = [&](size_t bytes) -> char* {
    char* r = p + off;
    off += (bytes + 255) & ~(size_t)255;
    return r;
  };
  float* cur    = (float*)alloc((size_t)N*64*4);
  unsigned short* xnb = (unsigned short*)alloc((size_t)N*64*2);
  unsigned short* o_buf = (unsigned short*)alloc((size_t)3*N*512*2);
  float* enc2   = (float*)alloc((size_t)N*32*4);
  float* lse    = (float*)alloc((size_t)3*N*8*4);
  unsigned long long* keys = (unsigned long long*)alloc((size_t)3*N*8);
  int* idx      = (int*)alloc((size_t)3*N*4);
  unsigned short* wqkvT = (unsigned short*)alloc((size_t)4*3*512*64*2);
  unsigned short* woT   = (unsigned short*)alloc((size_t)4*64*512*2);
  unsigned short* mqk   = (unsigned short*)alloc((size_t)4*8*64*64*2);
  unsigned* mm  = (unsigned*)alloc(256);
  float* whead  = (float*)alloc(256);

  // ---- weight convert/transpose + M + whead (all layers, once) ----
  wconv_kernel<<<2048, 256, 0, stream>>>(wq, wk, wv, wo, wqkvT, woT);
  mqk_kernel<<<32, 256, 0, stream>>>(wq, wk, mqk);
  whead_kernel<<<32, 64, 0, stream>>>(rpe_W, whead);

  // ---- sort keys (3 hash rounds, once) ----
  minmax_init_kernel<<<1, 64, 0, stream>>>(mm);
  minmax_reduce_kernel<<<64, 256, 0, stream>>>(coords, hash_proj, mm, N);
  make_keys_kernel<<<(N+255)/256, 256, 0, stream>>>(coords, batch, hash_proj, mm, keys, N);
  bitonic_local_full2k_kernel<<<dim3(N/2048, 3), 1024, 0, stream>>>(keys, N);
  for (int kk = 4096; kk <= N; kk <<= 1){
    for (int j = kk >> 1; j >= 2048; j >>= 1)
      bitonic_global_kernel<<<dim3(N/256, 3), 256, 0, stream>>>(keys, N, kk, j);
    bitonic_local_merge2k_kernel<<<dim3(N/2048, 3), 1024, 0, stream>>>(keys, N, kk);
  }
  extract_idx_kernel<<<(3*N+255)/256, 256, 0, stream>>>(keys, idx, 3*N);

  // ---- encoder (+ fused layer-0 LN) + feats[0] contribution to enc2 ----
  encoder_kernel<<<N/4, 256, 0, stream>>>(x, enc_W1, enc_b1, enc_W2, enc_b2,
      ln1_g, ln1_b, cur, xnb, N);
  enc2_accum_kernel<<<N/32, 256, 0, stream>>>(cur, W_cat, enc2, 0, 1, N);

  // ---- layers ----
  for (int l = 0; l < 4; ++l){
    attn_kernel<<<dim3(nb, 8, 3), 256, 0, stream>>>(xnb,
        wqkvT + (size_t)l*3*512*64, mqk + (size_t)l*8*4096,
        coords, batch, idx, whead + l*8, lse, o_buf, N);
    wo_mfma_kernel<<<N/64, 256, 0, stream>>>(o_buf, lse, woT + (size_t)l*64*512, cur, N);
    const float* nlg = (l < 3) ? (ln1_g + (l+1)*64) : nullptr;
    const float* nlb = (l < 3) ? (ln1_b + (l+1)*64) : nullptr;
    ffn_kernel<<<N/4, 256, 0, stream>>>(cur, ln2_g + l*64, ln2_b + l*64,
        ff_W1 + (size_t)l*64*64, ff_b1 + l*64, ff_W2 + (size_t)l*64*64, ff_b2 + l*64,
        nlg, nlb, xnb, N);
    enc2_accum_kernel<<<N/32, 256, 0, stream>>>(cur, W_cat, enc2, (l+1)*64, 0, N);
  }

  // ---- head ----
  head_kernel<<<N/8, 256, 0, stream>>>(enc2, mlp_W1, mlp_b1, mlp_W2, mlp_b2,
      beta_W1, beta_b1, beta_W2, beta_b2, coord_W1, coord_b1, coord_W2, coord_b2, outp, N);
}